// Round 18
// baseline (610.450 us; speedup 1.0000x reference)
//
#include <hip/hip_runtime.h>

#define T_DIM 2048
#define B_DIM 32
#define D_DIM 128
#define H_DIM 512
#define L_DIM 6
#define C_DIM 10
#define BN_EPS 1e-5f

constexpr int TB = T_DIM * B_DIM;           // 65536 rows (t-major, then b)
constexpr size_t TBH = (size_t)TB * H_DIM;  // 33,554,432 elements
constexpr size_t PKN = TBH / 2;             // packed u32 count (64 MB)

typedef short s16x8 __attribute__((ext_vector_type(8)));
typedef float f32x16 __attribute__((ext_vector_type(16)));

// ---- bf16 helpers (bit-level, RNE) ----
__device__ inline unsigned short f2bf(float f) {
  unsigned u = __float_as_uint(f);
  unsigned r = (u + 0x7FFFu + ((u >> 16) & 1u)) >> 16;
  return (unsigned short)r;
}
__device__ inline float bf2f(unsigned short b) {
  return __uint_as_float((unsigned)b << 16);
}

// De-interleave 8 packed u32 (evenT | oddT<<16) into two planar s16x8 in LDS.
__device__ inline void destage(uint4 q0, uint4 q1, unsigned short* dlo,
                               unsigned short* dhi) {
  uint4 lo, hi;
  lo.x = __builtin_amdgcn_perm(q0.y, q0.x, 0x05040100u);
  lo.y = __builtin_amdgcn_perm(q0.w, q0.z, 0x05040100u);
  lo.z = __builtin_amdgcn_perm(q1.y, q1.x, 0x05040100u);
  lo.w = __builtin_amdgcn_perm(q1.w, q1.z, 0x05040100u);
  hi.x = __builtin_amdgcn_perm(q0.y, q0.x, 0x07060302u);
  hi.y = __builtin_amdgcn_perm(q0.w, q0.z, 0x07060302u);
  hi.z = __builtin_amdgcn_perm(q1.y, q1.x, 0x07060302u);
  hi.w = __builtin_amdgcn_perm(q1.w, q1.z, 0x07060302u);
  *(uint4*)dlo = lo;
  *(uint4*)dhi = hi;
}

// ---------------------------------------------------------------------------
// bf16 MFMA GEMM over t-pair-packed activations, fully in-place:
//   z[t,b,o] = sum_k s[t,b,k] * W[o,k] + bias[o],  N = 512 fixed.
// Block i covers t-pair i (64 rows = 32 b x 2 t); packed u32 (t,b,h) lives
// at i*16384 + b*512 + h -> block reads AND writes exactly its own region.
// 512 threads (8 waves), wave = 64 rows x 64 cols; acc[0]=t-even, acc[1]=
// t-odd (same b). A staged PLANAR bf16 in K-chunks of BKC (double-buffered
// LDS; store-side destage for packed input). W: SINGLE bf16 (1-term MFMA),
// read from global in pre-swizzled fragment order with RING-4 register
// prefetch (R17-proven: 3-step lookahead covers L2 latency).
// Coalesced epilogue via LDS funnel.
// W fragment layout: elem (o,k) at ((c32*NIT+itg)*64 + kg*32 + r31)*8 + j.
// Also zeroes stats[0..1023] from block 0 (bn_fold precedes in stream order).
// ---------------------------------------------------------------------------
#define ROWS 64

template <int K, int BKC, bool PACKED_IN>
__global__ __launch_bounds__(512, 4) void gemm_mfma(
    const void* src, const unsigned short* __restrict__ Whi,
    const float* __restrict__ bias, uint* __restrict__ dstP, float* stats) {
  constexpr int NC = K / BKC;      // 2 (layer 0) or 4 (K=512)
  constexpr int NITC = BKC / 16;   // MFMA k-steps per chunk
  constexpr int NIT = K / 16;
  constexpr int GM = BKC / 8 - 1;  // granule swizzle mask
  __shared__ __align__(16) unsigned short AhS[2][ROWS * BKC];

  const int tid = threadIdx.x;
  if (blockIdx.x == 0) {  // fold zero_stats into the GEMM
    stats[tid] = 0.f;
    stats[tid + 512] = 0.f;
  }
  const int lane = tid & 63;
  const int wave = tid >> 6;  // 0..7 = col-group of 64
  const int r31 = lane & 31;
  const int kg = lane >> 5;

  const size_t pbase = (size_t)blockIdx.x * 16384;  // block's u32 region
  const uint* srcP = (const uint*)src;
  const float* srcF = (const float*)src;
  const size_t row0 = (size_t)blockIdx.x * ROWS;  // f32-path row base

  // W fragment bases for this wave's two col-frags (coalesced 16B/lane)
  const unsigned short* pWh0 =
      Whi + ((size_t)(wave * 2 + 0) * NIT * 64 + lane) * 8;
  const unsigned short* pWh1 =
      Whi + ((size_t)(wave * 2 + 1) * NIT * 64 + lane) * 8;

  // staging geometry
  const int sr0 = tid >> 4, sk0 = tid & 15;
  const int ss0 = sr0 * BKC + ((sk0 ^ (sr0 & GM)) << 3);
  const int ss1 = (sr0 + 32) * BKC + ((sk0 ^ ((sr0 + 32) & GM)) << 3);
  const int srf = tid >> 3, skf = tid & 7;
  const int ssf = srf * BKC + ((skf ^ (srf & GM)) << 3);

  auto cvt8 = [&](float4 a, float4 b) {
    float vv[8] = {a.x, a.y, a.z, a.w, b.x, b.y, b.z, b.w};
    s16x8 hi;
#pragma unroll
    for (int j = 0; j < 8; ++j) hi[j] = (short)f2bf(vv[j]);
    return hi;
  };

  // ---- prologue: stage chunk 0 ----
  if (PACKED_IN) {
    uint4 q0 = *(const uint4*)(srcP + pbase + sr0 * 512 + sk0 * 8);
    uint4 q1 = *(const uint4*)(srcP + pbase + sr0 * 512 + sk0 * 8 + 4);
    destage(q0, q1, &AhS[0][ss0], &AhS[0][ss1]);
  } else {
    const size_t g = (row0 + srf) * K + skf * 8;
    *(s16x8*)&AhS[0][ssf] =
        cvt8(*(const float4*)(srcF + g), *(const float4*)(srcF + g + 4));
  }
  // ---- W ring prologue: fragments itg=0,1,2 into slots 0,1,2 ----
  s16x8 whr[4][2];
#pragma unroll
  for (int s = 0; s < 3; ++s) {
    whr[s][0] = *(const s16x8*)(pWh0 + (size_t)s * 512);
    whr[s][1] = *(const s16x8*)(pWh1 + (size_t)s * 512);
  }
  __syncthreads();

  f32x16 acc[2][2] = {};
  uint4 q0, q1;   // in-flight next-chunk A (packed)
  float4 f0, f1;  // in-flight next-chunk A (f32)
#pragma unroll
  for (int c = 0; c < NC; ++c) {
    if (c + 1 < NC) {  // issue next chunk's loads (hide under MFMAs)
      if (PACKED_IN) {
        q0 = *(const uint4*)(srcP + pbase + sr0 * 512 + (c + 1) * BKC +
                             sk0 * 8);
        q1 = *(const uint4*)(srcP + pbase + sr0 * 512 + (c + 1) * BKC +
                             sk0 * 8 + 4);
      } else {
        const size_t g = (row0 + srf) * K + (c + 1) * BKC + skf * 8;
        f0 = *(const float4*)(srcF + g);
        f1 = *(const float4*)(srcF + g + 4);
      }
    }
    const int bsel = c & 1;
#pragma unroll
    for (int it = 0; it < NITC; ++it) {
      const int itg = c * NITC + it;
      const int sl = itg & 3;
      if (itg + 3 < NIT) {  // ring-4 W prefetch (3-step lookahead)
        const int sp = (itg + 3) & 3;
        whr[sp][0] = *(const s16x8*)(pWh0 + (size_t)(itg + 3) * 512);
        whr[sp][1] = *(const s16x8*)(pWh1 + (size_t)(itg + 3) * 512);
      }
      const int gi = it * 2 + kg;
      s16x8 ah[2];
#pragma unroll
      for (int rf = 0; rf < 2; ++rf) {
        const int row = rf * 32 + r31;
        ah[rf] =
            *(const s16x8*)&AhS[bsel][row * BKC + ((gi ^ (row & GM)) << 3)];
      }
      // 4 independent MFMAs (1-term: A * Whi)
#pragma unroll
      for (int cf = 0; cf < 2; ++cf)
#pragma unroll
        for (int rf = 0; rf < 2; ++rf)
          acc[rf][cf] = __builtin_amdgcn_mfma_f32_32x32x16_bf16(
              ah[rf], whr[sl][cf], acc[rf][cf], 0, 0, 0);
    }
    if (c + 1 < NC) {  // stage next chunk into the other LDS buffer
      const int nb = (c + 1) & 1;
      if (PACKED_IN) {
        destage(q0, q1, &AhS[nb][ss0], &AhS[nb][ss1]);
      } else {
        *(s16x8*)&AhS[nb][ssf] = cvt8(f0, f1);
      }
      __syncthreads();
    }
  }

  // ---- epilogue (coalesced via LDS funnel) ----
  // acc[0]=t-even, acc[1]=t-odd (same b). mb = (r&3)+8*(r>>2)+4*kg = b.
  {
    uint* Cs = (uint*)&AhS[0][0];
    constexpr int CAP = ROWS * BKC;  // total u32 across both LDS buffers
    constexpr int RP = CAP / 512;    // rows per pass (16 or 8)
    constexpr int NP = 32 / RP;      // passes (2 or 4)
    constexpr int NQ = CAP / 2048;   // uint4 copies per thread per pass
    const int o0 = wave * 64 + r31;
    const float bb0 = bias[o0];
    const float bb1 = bias[o0 + 32];
    __syncthreads();  // all A ds_reads done before LDS reuse
#pragma unroll
    for (int p = 0; p < NP; ++p) {
#pragma unroll
      for (int j = 0; j < RP / 2; ++j) {
        const int r = p * (RP / 2) + j;
        const int mb = (r & 3) + 8 * (r >> 2) + 4 * kg;
        const int lr = mb - p * RP;
        const float e0 = acc[0][0][r] + bb0;
        const float d0 = acc[1][0][r] + bb0;
        const float e1 = acc[0][1][r] + bb1;
        const float d1 = acc[1][1][r] + bb1;
        Cs[lr * 512 + o0] = (uint)f2bf(e0) | ((uint)f2bf(d0) << 16);
        Cs[lr * 512 + o0 + 32] = (uint)f2bf(e1) | ((uint)f2bf(d1) << 16);
      }
      __syncthreads();  // funnel writes visible
#pragma unroll
      for (int qd = 0; qd < NQ; ++qd) {
        uint4 v = *(const uint4*)&Cs[qd * 2048 + tid * 4];
        *(uint4*)&dstP[pbase + (size_t)p * CAP + qd * 2048 + tid * 4] = v;
      }
      if (p + 1 < NP) __syncthreads();  // copy reads done before overwrite
    }
  }
}

// ---------------------------------------------------------------------------
// IndRNN scan over packed z (u32 = bf16 z[2i] | bf16 z[2i+1]<<16), in-place:
// overwrites each u32 with packed bf16 s (bit-RNE). State in f32; stats
// accumulated on the ROUNDED s (what the next GEMM consumes).
// R18: TRIPLE-buffer rotation (va/vb/vc, period 3) -- compute chunk n while
// chunks n+1 AND n+2 stream. R17's double-buffer held only 8 KB/CU in
// flight vs the ~9 KB latency-BW product (1 wave/CU, nothing else to hide
// latency) -> 56us at 22% of HBM peak with VALUBusy 14%. The vm-queue
// (63 instrs, stores included) now stays full: ~16 KB in flight.
// One thread per (b,h); CH=32 u32 chunks.
// ---------------------------------------------------------------------------
__global__ __launch_bounds__(64) void indrnn_scan(uint* __restrict__ z,
                                                  const float* __restrict__ u,
                                                  float* __restrict__ stats) {
  const int gid = blockIdx.x * 64 + threadIdx.x;  // 0..16383
  const int h = gid & (H_DIM - 1);
  const float uu = u[h];
  float hh = 0.f, sum = 0.f, sumsq = 0.f;
  uint* p = z + gid;
  constexpr int STRIDE = B_DIM * H_DIM;  // 16384 u32
  constexpr int NI = T_DIM / 2;          // 1024 packed items per chain
  constexpr int CH = 32;
  constexpr int NCH = NI / CH;  // 32 chunks
  uint va[CH], vb[CH], vc[CH];

#define LOADC(dst, ck)                                          \
  _Pragma("unroll") for (int c = 0; c < CH; ++c) dst[c] =       \
      p[(size_t)((ck) * CH + c) * STRIDE];
#define COMPC(dst)                                              \
  _Pragma("unroll") for (int c = 0; c < CH; ++c) {              \
    uint pk = dst[c];                                           \
    float ze = __uint_as_float(pk << 16);                       \
    float zo = __uint_as_float(pk & 0xffff0000u);               \
    hh = fmaxf(ze + uu * hh, 0.f);                              \
    unsigned short he = f2bf(hh);                               \
    float se = bf2f(he);                                        \
    sum += se; sumsq += se * se;                                \
    hh = fmaxf(zo + uu * hh, 0.f);                              \
    unsigned short ho = f2bf(hh);                               \
    float so = bf2f(ho);                                        \
    sum += so; sumsq += so * so;                                \
    dst[c] = (uint)he | ((uint)ho << 16);                       \
  }
#define STOREC(dst, ck)                                         \
  _Pragma("unroll") for (int c = 0; c < CH; ++c)                \
      p[(size_t)((ck) * CH + c) * STRIDE] = dst[c];

  LOADC(va, 0)
  LOADC(vb, 1)
  for (int i = 0; i < NCH - 2; i += 3) {  // i = 0,3,...,27
    LOADC(vc, i + 2)
    COMPC(va)
    STOREC(va, i)
    LOADC(va, i + 3)
    COMPC(vb)
    STOREC(vb, i + 1)
    LOADC(vb, i + 4)
    COMPC(vc)
    STOREC(vc, i + 2)
  }
  // tail: chunks 30 (va), 31 (vb)
  COMPC(va)
  STOREC(va, NCH - 2)
  COMPC(vb)
  STOREC(vb, NCH - 1)
#undef LOADC
#undef COMPC
#undef STOREC
  atomicAdd(&stats[h], sum);
  atomicAdd(&stats[H_DIM + h], sumsq);
}

__global__ __launch_bounds__(64) void fill_sentinel(float* __restrict__ out,
                                                    int n) {
  for (int i = threadIdx.x; i < n; i += 64) out[i] = 1.0e6f;
}

// ---------------------------------------------------------------------------
// Convert raw f32 weights (layer 0) to bf16 in fragment-swizzled order.
// ---------------------------------------------------------------------------
template <int K>
__global__ __launch_bounds__(256) void convert_w(
    const float* __restrict__ W, unsigned short* __restrict__ Whi) {
  constexpr int NIT = K / 16;
  int i = blockIdx.x * 256 + threadIdx.x;
  if (i < H_DIM * K) {
    int o = i / K, k = i % K;
    size_t idx =
        ((size_t)((o >> 5) * NIT + (k >> 4)) * 64 + ((k >> 3) & 1) * 32 +
         (o & 31)) * 8 + (k & 7);
    Whi[idx] = f2bf(W[i]);
  }
}

// ---------------------------------------------------------------------------
// Fold BN of previous layer into next layer's weights, emit swizzled bf16:
//   a[i] = gamma[i]*rsqrt(var[i]+eps); c[i] = beta[i] - mean[i]*a[i]
//   Wf[o,i] = Wn[o,i]*a[i];  bf[o] = bn[o] + sum_i Wn[o,i]*c[i]
// ---------------------------------------------------------------------------
__global__ __launch_bounds__(256) void bn_fold(
    const float* __restrict__ stats, const float* __restrict__ gamma,
    const float* __restrict__ beta, const float* __restrict__ Wn,
    const float* __restrict__ bn, unsigned short* __restrict__ Whi,
    float* __restrict__ bf) {
  constexpr int NIT = H_DIM / 16;
  const int o = blockIdx.x;
  const int tid = threadIdx.x;
  constexpr float invTB = 1.f / (float)(T_DIM * B_DIM);
  float part = 0.f;
  for (int i = tid; i < H_DIM; i += 256) {
    float mean = stats[i] * invTB;
    float var = stats[H_DIM + i] * invTB - mean * mean;
    float a = gamma[i] * rsqrtf(var + BN_EPS);
    float c = beta[i] - mean * a;
    float w = Wn[(size_t)o * H_DIM + i];
    size_t idx =
        ((size_t)((o >> 5) * NIT + (i >> 4)) * 64 + ((i >> 3) & 1) * 32 +
         (o & 31)) * 8 + (i & 7);
    Whi[idx] = f2bf(w * a);
    part += w * c;
  }
  __shared__ float red[256];
  red[tid] = part;
  __syncthreads();
  for (int s = 128; s > 0; s >>= 1) {
    if (tid < s) red[tid] += red[tid + s];
    __syncthreads();
  }
  if (tid == 0) bf[o] = bn[o] + red[0];
}

// ---------------------------------------------------------------------------
// Final: out[b,c] = sum_i (s5[T-1,b,i]*a5[i] + c5[i]) * Wout[c,i] + bout[c]
// s5 packed: t=2047 is the HIGH half of packed item i=1023.
// ---------------------------------------------------------------------------
__global__ __launch_bounds__(64) void final_out(const uint* __restrict__ s5,
                                                const float* __restrict__ stats,
                                                const float* __restrict__ gamma,
                                                const float* __restrict__ beta,
                                                const float* __restrict__ Wout,
                                                const float* __restrict__ bout,
                                                float* __restrict__ out) {
  const int b = blockIdx.x / C_DIM, cls = blockIdx.x % C_DIM;
  const int lane = threadIdx.x;
  constexpr float invTB = 1.f / (float)(T_DIM * B_DIM);
  const uint* srow =
      s5 + (size_t)(T_DIM / 2 - 1) * B_DIM * H_DIM + (size_t)b * H_DIM;
  float part = 0.f;
  for (int i = lane; i < H_DIM; i += 64) {
    float mean = stats[i] * invTB;
    float var = stats[H_DIM + i] * invTB - mean * mean;
    float a = gamma[i] * rsqrtf(var + BN_EPS);
    float c = beta[i] - mean * a;
    float sval = __uint_as_float(srow[i] & 0xffff0000u);
    part += (sval * a + c) * Wout[(size_t)cls * H_DIM + i];
  }
#pragma unroll
  for (int off = 32; off > 0; off >>= 1) part += __shfl_down(part, off);
  if (lane == 0) out[b * C_DIM + cls] = part + bout[cls];
}

// ---------------------------------------------------------------------------
extern "C" void kernel_launch(void* const* d_in, const int* in_sizes, int n_in,
                              void* d_out, int out_size, void* d_ws,
                              size_t ws_size, hipStream_t stream) {
  const float* x     = (const float*)d_in[0];
  const float* W0    = (const float*)d_in[1];
  const float* b0    = (const float*)d_in[2];
  const float* Wh    = (const float*)d_in[3];
  const float* bh    = (const float*)d_in[4];
  const float* u     = (const float*)d_in[5];
  const float* gamma = (const float*)d_in[6];
  const float* beta  = (const float*)d_in[7];
  const float* Wout  = (const float*)d_in[8];
  const float* bout  = (const float*)d_in[9];
  float* out = (float*)d_out;

  const size_t need = PKN * sizeof(uint) +
                      (size_t)H_DIM * H_DIM * sizeof(unsigned short) +
                      3 * H_DIM * sizeof(float);
  if (ws_size < need) {
    fill_sentinel<<<1, 64, 0, stream>>>(out, out_size);
    return;
  }

  uint* buf = (uint*)d_ws;                             // 64 MB packed acts
  unsigned short* Whi = (unsigned short*)(buf + PKN);  // 512 KB
  float* bf = (float*)(Whi + (size_t)H_DIM * H_DIM);   // 2 KB
  float* stats = bf + H_DIM;                           // 4 KB

  const int gemm_blocks = TB / ROWS;  // 1024
  const int scan_blocks = (B_DIM * H_DIM) / 64;

  // ---- layer 0: x (f32, K=128, BKC=64 -> NC=2 pipelined) -> buf ----
  convert_w<D_DIM><<<(H_DIM * D_DIM + 255) / 256, 256, 0, stream>>>(W0, Whi);
  gemm_mfma<D_DIM, 64, false><<<gemm_blocks, 512, 0, stream>>>(x, Whi, b0,
                                                               buf, stats);
  indrnn_scan<<<scan_blocks, 64, 0, stream>>>(buf, u, stats);

  // ---- layers 1..5: fully in-place on the 64 MB packed buffer ----
  for (int l = 1; l < L_DIM; ++l) {
    bn_fold<<<H_DIM, 256, 0, stream>>>(
        stats, gamma + (size_t)(l - 1) * H_DIM, beta + (size_t)(l - 1) * H_DIM,
        Wh + (size_t)(l - 1) * H_DIM * H_DIM, bh + (size_t)(l - 1) * H_DIM,
        Whi, bf);
    gemm_mfma<H_DIM, 128, true><<<gemm_blocks, 512, 0, stream>>>(
        buf, Whi, bf, buf, stats);
    indrnn_scan<<<scan_blocks, 64, 0, stream>>>(buf, u + (size_t)l * H_DIM,
                                                stats);
  }

  // ---- final projection (BN of layer 5 applied on the fly) ----
  final_out<<<B_DIM * C_DIM, 64, 0, stream>>>(
      buf, stats, gamma + 5 * (size_t)H_DIM, beta + 5 * (size_t)H_DIM, Wout,
      bout, out);
}

// Round 19
// 591.831 us; speedup vs baseline: 1.0315x; 1.0315x over previous
//
#include <hip/hip_runtime.h>

#define T_DIM 2048
#define B_DIM 32
#define D_DIM 128
#define H_DIM 512
#define L_DIM 6
#define C_DIM 10
#define BN_EPS 1e-5f

constexpr int TB = T_DIM * B_DIM;           // 65536 rows (t-major, then b)
constexpr size_t TBH = (size_t)TB * H_DIM;  // 33,554,432 elements
constexpr size_t PKN = TBH / 2;             // packed u32 count (64 MB)

typedef short s16x8 __attribute__((ext_vector_type(8)));
typedef float f32x16 __attribute__((ext_vector_type(16)));

// ---- bf16 helpers (bit-level, RNE) ----
__device__ inline unsigned short f2bf(float f) {
  unsigned u = __float_as_uint(f);
  unsigned r = (u + 0x7FFFu + ((u >> 16) & 1u)) >> 16;
  return (unsigned short)r;
}
__device__ inline float bf2f(unsigned short b) {
  return __uint_as_float((unsigned)b << 16);
}

// De-interleave 8 packed u32 (evenT | oddT<<16) into two planar s16x8 in LDS.
__device__ inline void destage(uint4 q0, uint4 q1, unsigned short* dlo,
                               unsigned short* dhi) {
  uint4 lo, hi;
  lo.x = __builtin_amdgcn_perm(q0.y, q0.x, 0x05040100u);
  lo.y = __builtin_amdgcn_perm(q0.w, q0.z, 0x05040100u);
  lo.z = __builtin_amdgcn_perm(q1.y, q1.x, 0x05040100u);
  lo.w = __builtin_amdgcn_perm(q1.w, q1.z, 0x05040100u);
  hi.x = __builtin_amdgcn_perm(q0.y, q0.x, 0x07060302u);
  hi.y = __builtin_amdgcn_perm(q0.w, q0.z, 0x07060302u);
  hi.z = __builtin_amdgcn_perm(q1.y, q1.x, 0x07060302u);
  hi.w = __builtin_amdgcn_perm(q1.w, q1.z, 0x07060302u);
  *(uint4*)dlo = lo;
  *(uint4*)dhi = hi;
}

// ---------------------------------------------------------------------------
// bf16 MFMA GEMM over t-pair-packed activations, fully in-place:
//   z[t,b,o] = sum_k s[t,b,k] * W[o,k] + bias[o],  N = 512 fixed.
// Block i covers t-pair i (64 rows = 32 b x 2 t); packed u32 (t,b,h) lives
// at i*16384 + b*512 + h -> block reads AND writes exactly its own region.
// 512 threads (8 waves), wave = 64 rows x 64 cols; acc[0]=t-even, acc[1]=
// t-odd (same b). A staged PLANAR bf16 in K-chunks of BKC (double-buffered
// LDS; store-side destage for packed input). W: SINGLE bf16 (1-term MFMA),
// read from global in pre-swizzled fragment order with RING-4 register
// prefetch (R17-proven: 3-step lookahead covers L2 latency).
// Coalesced epilogue via LDS funnel.
// W fragment layout: elem (o,k) at ((c32*NIT+itg)*64 + kg*32 + r31)*8 + j.
// Also zeroes stats[0..1023] from block 0 (bn_fold precedes in stream order).
// ---------------------------------------------------------------------------
#define ROWS 64

template <int K, int BKC, bool PACKED_IN>
__global__ __launch_bounds__(512, 4) void gemm_mfma(
    const void* src, const unsigned short* __restrict__ Whi,
    const float* __restrict__ bias, uint* __restrict__ dstP, float* stats) {
  constexpr int NC = K / BKC;      // 2 (layer 0) or 4 (K=512)
  constexpr int NITC = BKC / 16;   // MFMA k-steps per chunk
  constexpr int NIT = K / 16;
  constexpr int GM = BKC / 8 - 1;  // granule swizzle mask
  __shared__ __align__(16) unsigned short AhS[2][ROWS * BKC];

  const int tid = threadIdx.x;
  if (blockIdx.x == 0) {  // fold zero_stats into the GEMM
    stats[tid] = 0.f;
    stats[tid + 512] = 0.f;
  }
  const int lane = tid & 63;
  const int wave = tid >> 6;  // 0..7 = col-group of 64
  const int r31 = lane & 31;
  const int kg = lane >> 5;

  const size_t pbase = (size_t)blockIdx.x * 16384;  // block's u32 region
  const uint* srcP = (const uint*)src;
  const float* srcF = (const float*)src;
  const size_t row0 = (size_t)blockIdx.x * ROWS;  // f32-path row base

  // W fragment bases for this wave's two col-frags (coalesced 16B/lane)
  const unsigned short* pWh0 =
      Whi + ((size_t)(wave * 2 + 0) * NIT * 64 + lane) * 8;
  const unsigned short* pWh1 =
      Whi + ((size_t)(wave * 2 + 1) * NIT * 64 + lane) * 8;

  // staging geometry
  const int sr0 = tid >> 4, sk0 = tid & 15;
  const int ss0 = sr0 * BKC + ((sk0 ^ (sr0 & GM)) << 3);
  const int ss1 = (sr0 + 32) * BKC + ((sk0 ^ ((sr0 + 32) & GM)) << 3);
  const int srf = tid >> 3, skf = tid & 7;
  const int ssf = srf * BKC + ((skf ^ (srf & GM)) << 3);

  auto cvt8 = [&](float4 a, float4 b) {
    float vv[8] = {a.x, a.y, a.z, a.w, b.x, b.y, b.z, b.w};
    s16x8 hi;
#pragma unroll
    for (int j = 0; j < 8; ++j) hi[j] = (short)f2bf(vv[j]);
    return hi;
  };

  // ---- prologue: stage chunk 0 ----
  if (PACKED_IN) {
    uint4 q0 = *(const uint4*)(srcP + pbase + sr0 * 512 + sk0 * 8);
    uint4 q1 = *(const uint4*)(srcP + pbase + sr0 * 512 + sk0 * 8 + 4);
    destage(q0, q1, &AhS[0][ss0], &AhS[0][ss1]);
  } else {
    const size_t g = (row0 + srf) * K + skf * 8;
    *(s16x8*)&AhS[0][ssf] =
        cvt8(*(const float4*)(srcF + g), *(const float4*)(srcF + g + 4));
  }
  // ---- W ring prologue: fragments itg=0,1,2 into slots 0,1,2 ----
  s16x8 whr[4][2];
#pragma unroll
  for (int s = 0; s < 3; ++s) {
    whr[s][0] = *(const s16x8*)(pWh0 + (size_t)s * 512);
    whr[s][1] = *(const s16x8*)(pWh1 + (size_t)s * 512);
  }
  __syncthreads();

  f32x16 acc[2][2] = {};
  uint4 q0, q1;   // in-flight next-chunk A (packed)
  float4 f0, f1;  // in-flight next-chunk A (f32)
#pragma unroll
  for (int c = 0; c < NC; ++c) {
    if (c + 1 < NC) {  // issue next chunk's loads (hide under MFMAs)
      if (PACKED_IN) {
        q0 = *(const uint4*)(srcP + pbase + sr0 * 512 + (c + 1) * BKC +
                             sk0 * 8);
        q1 = *(const uint4*)(srcP + pbase + sr0 * 512 + (c + 1) * BKC +
                             sk0 * 8 + 4);
      } else {
        const size_t g = (row0 + srf) * K + (c + 1) * BKC + skf * 8;
        f0 = *(const float4*)(srcF + g);
        f1 = *(const float4*)(srcF + g + 4);
      }
    }
    const int bsel = c & 1;
#pragma unroll
    for (int it = 0; it < NITC; ++it) {
      const int itg = c * NITC + it;
      const int sl = itg & 3;
      if (itg + 3 < NIT) {  // ring-4 W prefetch (3-step lookahead)
        const int sp = (itg + 3) & 3;
        whr[sp][0] = *(const s16x8*)(pWh0 + (size_t)(itg + 3) * 512);
        whr[sp][1] = *(const s16x8*)(pWh1 + (size_t)(itg + 3) * 512);
      }
      const int gi = it * 2 + kg;
      s16x8 ah[2];
#pragma unroll
      for (int rf = 0; rf < 2; ++rf) {
        const int row = rf * 32 + r31;
        ah[rf] =
            *(const s16x8*)&AhS[bsel][row * BKC + ((gi ^ (row & GM)) << 3)];
      }
      // 4 independent MFMAs (1-term: A * Whi)
#pragma unroll
      for (int cf = 0; cf < 2; ++cf)
#pragma unroll
        for (int rf = 0; rf < 2; ++rf)
          acc[rf][cf] = __builtin_amdgcn_mfma_f32_32x32x16_bf16(
              ah[rf], whr[sl][cf], acc[rf][cf], 0, 0, 0);
    }
    if (c + 1 < NC) {  // stage next chunk into the other LDS buffer
      const int nb = (c + 1) & 1;
      if (PACKED_IN) {
        destage(q0, q1, &AhS[nb][ss0], &AhS[nb][ss1]);
      } else {
        *(s16x8*)&AhS[nb][ssf] = cvt8(f0, f1);
      }
      __syncthreads();
    }
  }

  // ---- epilogue (coalesced via LDS funnel) ----
  // acc[0]=t-even, acc[1]=t-odd (same b). mb = (r&3)+8*(r>>2)+4*kg = b.
  {
    uint* Cs = (uint*)&AhS[0][0];
    constexpr int CAP = ROWS * BKC;  // total u32 across both LDS buffers
    constexpr int RP = CAP / 512;    // rows per pass (16 or 8)
    constexpr int NP = 32 / RP;      // passes (2 or 4)
    constexpr int NQ = CAP / 2048;   // uint4 copies per thread per pass
    const int o0 = wave * 64 + r31;
    const float bb0 = bias[o0];
    const float bb1 = bias[o0 + 32];
    __syncthreads();  // all A ds_reads done before LDS reuse
#pragma unroll
    for (int p = 0; p < NP; ++p) {
#pragma unroll
      for (int j = 0; j < RP / 2; ++j) {
        const int r = p * (RP / 2) + j;
        const int mb = (r & 3) + 8 * (r >> 2) + 4 * kg;
        const int lr = mb - p * RP;
        const float e0 = acc[0][0][r] + bb0;
        const float d0 = acc[1][0][r] + bb0;
        const float e1 = acc[0][1][r] + bb1;
        const float d1 = acc[1][1][r] + bb1;
        Cs[lr * 512 + o0] = (uint)f2bf(e0) | ((uint)f2bf(d0) << 16);
        Cs[lr * 512 + o0 + 32] = (uint)f2bf(e1) | ((uint)f2bf(d1) << 16);
      }
      __syncthreads();  // funnel writes visible
#pragma unroll
      for (int qd = 0; qd < NQ; ++qd) {
        uint4 v = *(const uint4*)&Cs[qd * 2048 + tid * 4];
        *(uint4*)&dstP[pbase + (size_t)p * CAP + qd * 2048 + tid * 4] = v;
      }
      if (p + 1 < NP) __syncthreads();  // copy reads done before overwrite
    }
  }
}

// ---------------------------------------------------------------------------
// IndRNN scan over packed z (u32 = bf16 z[2i] | bf16 z[2i+1]<<16), in-place:
// overwrites each u32 with packed bf16 s (bit-RNE). State in f32; stats
// accumulated on the ROUNDED s (what the next GEMM consumes).
// R19: 256-thread blocks (4 waves, 1/SIMD) -- R17/R18 ran 1 wave/CU with
// ZERO thread-level latency hiding (56us, 22% HBM, VALUBusy 14%); R18's
// deeper per-wave pipeline spilled (regressed). TLP is the right axis:
// 3 other waves issue loads while one computes. 64 CUs active; per-CU
// demand ~100 GB/s = 42 B/cyc, under the L1 port. Inner structure is the
// R17-proven CH=32 register double-buffer.
// One thread per (b,h).
// ---------------------------------------------------------------------------
__global__ __launch_bounds__(256) void indrnn_scan(uint* __restrict__ z,
                                                   const float* __restrict__ u,
                                                   float* __restrict__ stats) {
  const int gid = blockIdx.x * 256 + threadIdx.x;  // 0..16383
  const int h = gid & (H_DIM - 1);
  const float uu = u[h];
  float hh = 0.f, sum = 0.f, sumsq = 0.f;
  uint* p = z + gid;
  constexpr int STRIDE = B_DIM * H_DIM;  // 16384 u32
  constexpr int NI = T_DIM / 2;          // 1024 packed items per chain
  constexpr int CH = 32;
  constexpr int NCH = NI / CH;  // 32 chunks
  uint va[CH], vb[CH];

#define LOADC(dst, base)                                        \
  _Pragma("unroll") for (int c = 0; c < CH; ++c) dst[c] =       \
      p[(size_t)((base) + c) * STRIDE];
#define COMPC(dst)                                              \
  _Pragma("unroll") for (int c = 0; c < CH; ++c) {              \
    uint pk = dst[c];                                           \
    float ze = __uint_as_float(pk << 16);                       \
    float zo = __uint_as_float(pk & 0xffff0000u);               \
    hh = fmaxf(ze + uu * hh, 0.f);                              \
    unsigned short he = f2bf(hh);                               \
    float se = bf2f(he);                                        \
    sum += se; sumsq += se * se;                                \
    hh = fmaxf(zo + uu * hh, 0.f);                              \
    unsigned short ho = f2bf(hh);                               \
    float so = bf2f(ho);                                        \
    sum += so; sumsq += so * so;                                \
    dst[c] = (uint)he | ((uint)ho << 16);                       \
  }
#define STOREC(dst, base)                                       \
  _Pragma("unroll") for (int c = 0; c < CH; ++c)                \
      p[(size_t)((base) + c) * STRIDE] = dst[c];

  LOADC(va, 0)
  for (int i = 0; i < (NCH - 2) / 2; ++i) {
    const int t0 = i * 2 * CH;
    LOADC(vb, t0 + CH)
    COMPC(va)
    STOREC(va, t0)
    LOADC(va, t0 + 2 * CH)
    COMPC(vb)
    STOREC(vb, t0 + CH)
  }
  {
    const int t0 = (NCH - 2) * CH;
    LOADC(vb, t0 + CH)
    COMPC(va)
    STOREC(va, t0)
    COMPC(vb)
    STOREC(vb, t0 + CH)
  }
#undef LOADC
#undef COMPC
#undef STOREC
  atomicAdd(&stats[h], sum);
  atomicAdd(&stats[H_DIM + h], sumsq);
}

__global__ __launch_bounds__(64) void fill_sentinel(float* __restrict__ out,
                                                    int n) {
  for (int i = threadIdx.x; i < n; i += 64) out[i] = 1.0e6f;
}

// ---------------------------------------------------------------------------
// Convert raw f32 weights (layer 0) to bf16 in fragment-swizzled order.
// ---------------------------------------------------------------------------
template <int K>
__global__ __launch_bounds__(256) void convert_w(
    const float* __restrict__ W, unsigned short* __restrict__ Whi) {
  constexpr int NIT = K / 16;
  int i = blockIdx.x * 256 + threadIdx.x;
  if (i < H_DIM * K) {
    int o = i / K, k = i % K;
    size_t idx =
        ((size_t)((o >> 5) * NIT + (k >> 4)) * 64 + ((k >> 3) & 1) * 32 +
         (o & 31)) * 8 + (k & 7);
    Whi[idx] = f2bf(W[i]);
  }
}

// ---------------------------------------------------------------------------
// Fold BN of previous layer into next layer's weights, emit swizzled bf16:
//   a[i] = gamma[i]*rsqrt(var[i]+eps); c[i] = beta[i] - mean[i]*a[i]
//   Wf[o,i] = Wn[o,i]*a[i];  bf[o] = bn[o] + sum_i Wn[o,i]*c[i]
// ---------------------------------------------------------------------------
__global__ __launch_bounds__(256) void bn_fold(
    const float* __restrict__ stats, const float* __restrict__ gamma,
    const float* __restrict__ beta, const float* __restrict__ Wn,
    const float* __restrict__ bn, unsigned short* __restrict__ Whi,
    float* __restrict__ bf) {
  constexpr int NIT = H_DIM / 16;
  const int o = blockIdx.x;
  const int tid = threadIdx.x;
  constexpr float invTB = 1.f / (float)(T_DIM * B_DIM);
  float part = 0.f;
  for (int i = tid; i < H_DIM; i += 256) {
    float mean = stats[i] * invTB;
    float var = stats[H_DIM + i] * invTB - mean * mean;
    float a = gamma[i] * rsqrtf(var + BN_EPS);
    float c = beta[i] - mean * a;
    float w = Wn[(size_t)o * H_DIM + i];
    size_t idx =
        ((size_t)((o >> 5) * NIT + (i >> 4)) * 64 + ((i >> 3) & 1) * 32 +
         (o & 31)) * 8 + (i & 7);
    Whi[idx] = f2bf(w * a);
    part += w * c;
  }
  __shared__ float red[256];
  red[tid] = part;
  __syncthreads();
  for (int s = 128; s > 0; s >>= 1) {
    if (tid < s) red[tid] += red[tid + s];
    __syncthreads();
  }
  if (tid == 0) bf[o] = bn[o] + red[0];
}

// ---------------------------------------------------------------------------
// Final: out[b,c] = sum_i (s5[T-1,b,i]*a5[i] + c5[i]) * Wout[c,i] + bout[c]
// s5 packed: t=2047 is the HIGH half of packed item i=1023.
// ---------------------------------------------------------------------------
__global__ __launch_bounds__(64) void final_out(const uint* __restrict__ s5,
                                                const float* __restrict__ stats,
                                                const float* __restrict__ gamma,
                                                const float* __restrict__ beta,
                                                const float* __restrict__ Wout,
                                                const float* __restrict__ bout,
                                                float* __restrict__ out) {
  const int b = blockIdx.x / C_DIM, cls = blockIdx.x % C_DIM;
  const int lane = threadIdx.x;
  constexpr float invTB = 1.f / (float)(T_DIM * B_DIM);
  const uint* srow =
      s5 + (size_t)(T_DIM / 2 - 1) * B_DIM * H_DIM + (size_t)b * H_DIM;
  float part = 0.f;
  for (int i = lane; i < H_DIM; i += 64) {
    float mean = stats[i] * invTB;
    float var = stats[H_DIM + i] * invTB - mean * mean;
    float a = gamma[i] * rsqrtf(var + BN_EPS);
    float c = beta[i] - mean * a;
    float sval = __uint_as_float(srow[i] & 0xffff0000u);
    part += (sval * a + c) * Wout[(size_t)cls * H_DIM + i];
  }
#pragma unroll
  for (int off = 32; off > 0; off >>= 1) part += __shfl_down(part, off);
  if (lane == 0) out[b * C_DIM + cls] = part + bout[cls];
}

// ---------------------------------------------------------------------------
extern "C" void kernel_launch(void* const* d_in, const int* in_sizes, int n_in,
                              void* d_out, int out_size, void* d_ws,
                              size_t ws_size, hipStream_t stream) {
  const float* x     = (const float*)d_in[0];
  const float* W0    = (const float*)d_in[1];
  const float* b0    = (const float*)d_in[2];
  const float* Wh    = (const float*)d_in[3];
  const float* bh    = (const float*)d_in[4];
  const float* u     = (const float*)d_in[5];
  const float* gamma = (const float*)d_in[6];
  const float* beta  = (const float*)d_in[7];
  const float* Wout  = (const float*)d_in[8];
  const float* bout  = (const float*)d_in[9];
  float* out = (float*)d_out;

  const size_t need = PKN * sizeof(uint) +
                      (size_t)H_DIM * H_DIM * sizeof(unsigned short) +
                      3 * H_DIM * sizeof(float);
  if (ws_size < need) {
    fill_sentinel<<<1, 64, 0, stream>>>(out, out_size);
    return;
  }

  uint* buf = (uint*)d_ws;                             // 64 MB packed acts
  unsigned short* Whi = (unsigned short*)(buf + PKN);  // 512 KB
  float* bf = (float*)(Whi + (size_t)H_DIM * H_DIM);   // 2 KB
  float* stats = bf + H_DIM;                           // 4 KB

  const int gemm_blocks = TB / ROWS;  // 1024
  const int scan_blocks = (B_DIM * H_DIM) / 256;  // 64 blocks x 4 waves

  // ---- layer 0: x (f32, K=128, BKC=64 -> NC=2 pipelined) -> buf ----
  convert_w<D_DIM><<<(H_DIM * D_DIM + 255) / 256, 256, 0, stream>>>(W0, Whi);
  gemm_mfma<D_DIM, 64, false><<<gemm_blocks, 512, 0, stream>>>(x, Whi, b0,
                                                               buf, stats);
  indrnn_scan<<<scan_blocks, 256, 0, stream>>>(buf, u, stats);

  // ---- layers 1..5: fully in-place on the 64 MB packed buffer ----
  for (int l = 1; l < L_DIM; ++l) {
    bn_fold<<<H_DIM, 256, 0, stream>>>(
        stats, gamma + (size_t)(l - 1) * H_DIM, beta + (size_t)(l - 1) * H_DIM,
        Wh + (size_t)(l - 1) * H_DIM * H_DIM, bh + (size_t)(l - 1) * H_DIM,
        Whi, bf);
    gemm_mfma<H_DIM, 128, true><<<gemm_blocks, 512, 0, stream>>>(
        buf, Whi, bf, buf, stats);
    indrnn_scan<<<scan_blocks, 256, 0, stream>>>(buf, u + (size_t)l * H_DIM,
                                                 stats);
  }

  // ---- final projection (BN of layer 5 applied on the fly) ----
  final_out<<<B_DIM * C_DIM, 64, 0, stream>>>(
      buf, stats, gamma + 5 * (size_t)H_DIM, beta + 5 * (size_t)H_DIM, Wout,
      bout, out);
}

// Round 20
// 589.994 us; speedup vs baseline: 1.0347x; 1.0031x over previous
//
#include <hip/hip_runtime.h>

#define T_DIM 2048
#define B_DIM 32
#define D_DIM 128
#define H_DIM 512
#define L_DIM 6
#define C_DIM 10
#define BN_EPS 1e-5f

constexpr int TB = T_DIM * B_DIM;           // 65536 rows (t-major, then b)
constexpr size_t TBH = (size_t)TB * H_DIM;  // 33,554,432 elements
constexpr size_t PKN = TBH / 2;             // packed u32 count (64 MB)

typedef short s16x8 __attribute__((ext_vector_type(8)));
typedef float f32x16 __attribute__((ext_vector_type(16)));

// ---- bf16 helpers (bit-level, RNE) ----
__device__ inline unsigned short f2bf(float f) {
  unsigned u = __float_as_uint(f);
  unsigned r = (u + 0x7FFFu + ((u >> 16) & 1u)) >> 16;
  return (unsigned short)r;
}
__device__ inline float bf2f(unsigned short b) {
  return __uint_as_float((unsigned)b << 16);
}

// De-interleave 8 packed u32 (evenT | oddT<<16) into two planar s16x8 in LDS.
__device__ inline void destage(uint4 q0, uint4 q1, unsigned short* dlo,
                               unsigned short* dhi) {
  uint4 lo, hi;
  lo.x = __builtin_amdgcn_perm(q0.y, q0.x, 0x05040100u);
  lo.y = __builtin_amdgcn_perm(q0.w, q0.z, 0x05040100u);
  lo.z = __builtin_amdgcn_perm(q1.y, q1.x, 0x05040100u);
  lo.w = __builtin_amdgcn_perm(q1.w, q1.z, 0x05040100u);
  hi.x = __builtin_amdgcn_perm(q0.y, q0.x, 0x07060302u);
  hi.y = __builtin_amdgcn_perm(q0.w, q0.z, 0x07060302u);
  hi.z = __builtin_amdgcn_perm(q1.y, q1.x, 0x07060302u);
  hi.w = __builtin_amdgcn_perm(q1.w, q1.z, 0x07060302u);
  *(uint4*)dlo = lo;
  *(uint4*)dhi = hi;
}

// ---------------------------------------------------------------------------
// bf16 MFMA GEMM over t-pair-packed activations (OUT-of-place, R20):
//   z[t,b,o] = sum_k s[t,b,k] * W[o,k] + bias[o],  N = 512 fixed.
// Block i covers t-pair i (64 rows = 32 b x 2 t); packed u32 (t,b,h) at
// i*16384 + b*512 + h in its buffer. Reads s from srcP (or f32 x), writes z
// to dstP (a DIFFERENT 64 MB buffer -- ping-pong, so the following scan's
// read and write streams never share an address range).
// 512 threads (8 waves), wave = 64 rows x 64 cols; acc[0]=t-even, acc[1]=
// t-odd (same b). A staged PLANAR bf16 in K-chunks of BKC (double-buffered
// LDS; store-side destage for packed input). W: SINGLE bf16 (1-term MFMA),
// pre-swizzled fragment order, RING-4 register prefetch (R17-proven).
// Coalesced epilogue via LDS funnel.
// W fragment layout: elem (o,k) at ((c32*NIT+itg)*64 + kg*32 + r31)*8 + j.
// Also zeroes stats[0..1023] from block 0 (bn_fold precedes in stream order).
// ---------------------------------------------------------------------------
#define ROWS 64

template <int K, int BKC, bool PACKED_IN>
__global__ __launch_bounds__(512, 4) void gemm_mfma(
    const void* src, const unsigned short* __restrict__ Whi,
    const float* __restrict__ bias, uint* __restrict__ dstP, float* stats) {
  constexpr int NC = K / BKC;      // 2 (layer 0) or 4 (K=512)
  constexpr int NITC = BKC / 16;   // MFMA k-steps per chunk
  constexpr int NIT = K / 16;
  constexpr int GM = BKC / 8 - 1;  // granule swizzle mask
  __shared__ __align__(16) unsigned short AhS[2][ROWS * BKC];

  const int tid = threadIdx.x;
  if (blockIdx.x == 0) {  // fold zero_stats into the GEMM
    stats[tid] = 0.f;
    stats[tid + 512] = 0.f;
  }
  const int lane = tid & 63;
  const int wave = tid >> 6;  // 0..7 = col-group of 64
  const int r31 = lane & 31;
  const int kg = lane >> 5;

  const size_t pbase = (size_t)blockIdx.x * 16384;  // block's u32 region
  const uint* srcP = (const uint*)src;
  const float* srcF = (const float*)src;
  const size_t row0 = (size_t)blockIdx.x * ROWS;  // f32-path row base

  // W fragment bases for this wave's two col-frags (coalesced 16B/lane)
  const unsigned short* pWh0 =
      Whi + ((size_t)(wave * 2 + 0) * NIT * 64 + lane) * 8;
  const unsigned short* pWh1 =
      Whi + ((size_t)(wave * 2 + 1) * NIT * 64 + lane) * 8;

  // staging geometry
  const int sr0 = tid >> 4, sk0 = tid & 15;
  const int ss0 = sr0 * BKC + ((sk0 ^ (sr0 & GM)) << 3);
  const int ss1 = (sr0 + 32) * BKC + ((sk0 ^ ((sr0 + 32) & GM)) << 3);
  const int srf = tid >> 3, skf = tid & 7;
  const int ssf = srf * BKC + ((skf ^ (srf & GM)) << 3);

  auto cvt8 = [&](float4 a, float4 b) {
    float vv[8] = {a.x, a.y, a.z, a.w, b.x, b.y, b.z, b.w};
    s16x8 hi;
#pragma unroll
    for (int j = 0; j < 8; ++j) hi[j] = (short)f2bf(vv[j]);
    return hi;
  };

  // ---- prologue: stage chunk 0 ----
  if (PACKED_IN) {
    uint4 q0 = *(const uint4*)(srcP + pbase + sr0 * 512 + sk0 * 8);
    uint4 q1 = *(const uint4*)(srcP + pbase + sr0 * 512 + sk0 * 8 + 4);
    destage(q0, q1, &AhS[0][ss0], &AhS[0][ss1]);
  } else {
    const size_t g = (row0 + srf) * K + skf * 8;
    *(s16x8*)&AhS[0][ssf] =
        cvt8(*(const float4*)(srcF + g), *(const float4*)(srcF + g + 4));
  }
  // ---- W ring prologue: fragments itg=0,1,2 into slots 0,1,2 ----
  s16x8 whr[4][2];
#pragma unroll
  for (int s = 0; s < 3; ++s) {
    whr[s][0] = *(const s16x8*)(pWh0 + (size_t)s * 512);
    whr[s][1] = *(const s16x8*)(pWh1 + (size_t)s * 512);
  }
  __syncthreads();

  f32x16 acc[2][2] = {};
  uint4 q0, q1;   // in-flight next-chunk A (packed)
  float4 f0, f1;  // in-flight next-chunk A (f32)
#pragma unroll
  for (int c = 0; c < NC; ++c) {
    if (c + 1 < NC) {  // issue next chunk's loads (hide under MFMAs)
      if (PACKED_IN) {
        q0 = *(const uint4*)(srcP + pbase + sr0 * 512 + (c + 1) * BKC +
                             sk0 * 8);
        q1 = *(const uint4*)(srcP + pbase + sr0 * 512 + (c + 1) * BKC +
                             sk0 * 8 + 4);
      } else {
        const size_t g = (row0 + srf) * K + (c + 1) * BKC + skf * 8;
        f0 = *(const float4*)(srcF + g);
        f1 = *(const float4*)(srcF + g + 4);
      }
    }
    const int bsel = c & 1;
#pragma unroll
    for (int it = 0; it < NITC; ++it) {
      const int itg = c * NITC + it;
      const int sl = itg & 3;
      if (itg + 3 < NIT) {  // ring-4 W prefetch (3-step lookahead)
        const int sp = (itg + 3) & 3;
        whr[sp][0] = *(const s16x8*)(pWh0 + (size_t)(itg + 3) * 512);
        whr[sp][1] = *(const s16x8*)(pWh1 + (size_t)(itg + 3) * 512);
      }
      const int gi = it * 2 + kg;
      s16x8 ah[2];
#pragma unroll
      for (int rf = 0; rf < 2; ++rf) {
        const int row = rf * 32 + r31;
        ah[rf] =
            *(const s16x8*)&AhS[bsel][row * BKC + ((gi ^ (row & GM)) << 3)];
      }
      // 4 independent MFMAs (1-term: A * Whi)
#pragma unroll
      for (int cf = 0; cf < 2; ++cf)
#pragma unroll
        for (int rf = 0; rf < 2; ++rf)
          acc[rf][cf] = __builtin_amdgcn_mfma_f32_32x32x16_bf16(
              ah[rf], whr[sl][cf], acc[rf][cf], 0, 0, 0);
    }
    if (c + 1 < NC) {  // stage next chunk into the other LDS buffer
      const int nb = (c + 1) & 1;
      if (PACKED_IN) {
        destage(q0, q1, &AhS[nb][ss0], &AhS[nb][ss1]);
      } else {
        *(s16x8*)&AhS[nb][ssf] = cvt8(f0, f1);
      }
      __syncthreads();
    }
  }

  // ---- epilogue (coalesced via LDS funnel) ----
  // acc[0]=t-even, acc[1]=t-odd (same b). mb = (r&3)+8*(r>>2)+4*kg = b.
  {
    uint* Cs = (uint*)&AhS[0][0];
    constexpr int CAP = ROWS * BKC;  // total u32 across both LDS buffers
    constexpr int RP = CAP / 512;    // rows per pass (16 or 8)
    constexpr int NP = 32 / RP;      // passes (2 or 4)
    constexpr int NQ = CAP / 2048;   // uint4 copies per thread per pass
    const int o0 = wave * 64 + r31;
    const float bb0 = bias[o0];
    const float bb1 = bias[o0 + 32];
    __syncthreads();  // all A ds_reads done before LDS reuse
#pragma unroll
    for (int p = 0; p < NP; ++p) {
#pragma unroll
      for (int j = 0; j < RP / 2; ++j) {
        const int r = p * (RP / 2) + j;
        const int mb = (r & 3) + 8 * (r >> 2) + 4 * kg;
        const int lr = mb - p * RP;
        const float e0 = acc[0][0][r] + bb0;
        const float d0 = acc[1][0][r] + bb0;
        const float e1 = acc[0][1][r] + bb1;
        const float d1 = acc[1][1][r] + bb1;
        Cs[lr * 512 + o0] = (uint)f2bf(e0) | ((uint)f2bf(d0) << 16);
        Cs[lr * 512 + o0 + 32] = (uint)f2bf(e1) | ((uint)f2bf(d1) << 16);
      }
      __syncthreads();  // funnel writes visible
#pragma unroll
      for (int qd = 0; qd < NQ; ++qd) {
        uint4 v = *(const uint4*)&Cs[qd * 2048 + tid * 4];
        *(uint4*)&dstP[pbase + (size_t)p * CAP + qd * 2048 + tid * 4] = v;
      }
      if (p + 1 < NP) __syncthreads();  // copy reads done before overwrite
    }
  }
}

// ---------------------------------------------------------------------------
// IndRNN scan over packed z, OUT-of-place (R20): reads z from zsrc, writes
// packed bf16 s to sdst -- disjoint 64 MB buffers, so the read stream and
// the write stream never touch the same address range (R17/R18/R19 showed
// depth/TLP levers null; in-place RMW stream interference is the surviving
// hypothesis for the 1.8 TB/s cap). State in f32; stats accumulated on the
// ROUNDED s. One thread per (b,h); CH=32 chunks, register double-buffered
// (R17-proven structure); 256 blocks x 64 threads.
// ---------------------------------------------------------------------------
__global__ __launch_bounds__(64) void indrnn_scan(const uint* __restrict__ zsrc,
                                                  uint* __restrict__ sdst,
                                                  const float* __restrict__ u,
                                                  float* __restrict__ stats) {
  const int gid = blockIdx.x * 64 + threadIdx.x;  // 0..16383
  const int h = gid & (H_DIM - 1);
  const float uu = u[h];
  float hh = 0.f, sum = 0.f, sumsq = 0.f;
  const uint* ps = zsrc + gid;
  uint* pd = sdst + gid;
  constexpr int STRIDE = B_DIM * H_DIM;  // 16384 u32
  constexpr int NI = T_DIM / 2;          // 1024 packed items per chain
  constexpr int CH = 32;
  constexpr int NCH = NI / CH;  // 32 chunks
  uint va[CH], vb[CH];

#define LOADC(dst, base)                                        \
  _Pragma("unroll") for (int c = 0; c < CH; ++c) dst[c] =       \
      ps[(size_t)((base) + c) * STRIDE];
#define COMPC(dst)                                              \
  _Pragma("unroll") for (int c = 0; c < CH; ++c) {              \
    uint pk = dst[c];                                           \
    float ze = __uint_as_float(pk << 16);                       \
    float zo = __uint_as_float(pk & 0xffff0000u);               \
    hh = fmaxf(ze + uu * hh, 0.f);                              \
    unsigned short he = f2bf(hh);                               \
    float se = bf2f(he);                                        \
    sum += se; sumsq += se * se;                                \
    hh = fmaxf(zo + uu * hh, 0.f);                              \
    unsigned short ho = f2bf(hh);                               \
    float so = bf2f(ho);                                        \
    sum += so; sumsq += so * so;                                \
    dst[c] = (uint)he | ((uint)ho << 16);                       \
  }
#define STOREC(dst, base)                                       \
  _Pragma("unroll") for (int c = 0; c < CH; ++c)                \
      pd[(size_t)((base) + c) * STRIDE] = dst[c];

  LOADC(va, 0)
  for (int i = 0; i < (NCH - 2) / 2; ++i) {
    const int t0 = i * 2 * CH;
    LOADC(vb, t0 + CH)
    COMPC(va)
    STOREC(va, t0)
    LOADC(va, t0 + 2 * CH)
    COMPC(vb)
    STOREC(vb, t0 + CH)
  }
  {
    const int t0 = (NCH - 2) * CH;
    LOADC(vb, t0 + CH)
    COMPC(va)
    STOREC(va, t0)
    COMPC(vb)
    STOREC(vb, t0 + CH)
  }
#undef LOADC
#undef COMPC
#undef STOREC
  atomicAdd(&stats[h], sum);
  atomicAdd(&stats[H_DIM + h], sumsq);
}

__global__ __launch_bounds__(64) void fill_sentinel(float* __restrict__ out,
                                                    int n) {
  for (int i = threadIdx.x; i < n; i += 64) out[i] = 1.0e6f;
}

// ---------------------------------------------------------------------------
// Convert raw f32 weights (layer 0) to bf16 in fragment-swizzled order.
// ---------------------------------------------------------------------------
template <int K>
__global__ __launch_bounds__(256) void convert_w(
    const float* __restrict__ W, unsigned short* __restrict__ Whi) {
  constexpr int NIT = K / 16;
  int i = blockIdx.x * 256 + threadIdx.x;
  if (i < H_DIM * K) {
    int o = i / K, k = i % K;
    size_t idx =
        ((size_t)((o >> 5) * NIT + (k >> 4)) * 64 + ((k >> 3) & 1) * 32 +
         (o & 31)) * 8 + (k & 7);
    Whi[idx] = f2bf(W[i]);
  }
}

// ---------------------------------------------------------------------------
// Fold BN of previous layer into next layer's weights, emit swizzled bf16:
//   a[i] = gamma[i]*rsqrt(var[i]+eps); c[i] = beta[i] - mean[i]*a[i]
//   Wf[o,i] = Wn[o,i]*a[i];  bf[o] = bn[o] + sum_i Wn[o,i]*c[i]
// ---------------------------------------------------------------------------
__global__ __launch_bounds__(256) void bn_fold(
    const float* __restrict__ stats, const float* __restrict__ gamma,
    const float* __restrict__ beta, const float* __restrict__ Wn,
    const float* __restrict__ bn, unsigned short* __restrict__ Whi,
    float* __restrict__ bf) {
  constexpr int NIT = H_DIM / 16;
  const int o = blockIdx.x;
  const int tid = threadIdx.x;
  constexpr float invTB = 1.f / (float)(T_DIM * B_DIM);
  float part = 0.f;
  for (int i = tid; i < H_DIM; i += 256) {
    float mean = stats[i] * invTB;
    float var = stats[H_DIM + i] * invTB - mean * mean;
    float a = gamma[i] * rsqrtf(var + BN_EPS);
    float c = beta[i] - mean * a;
    float w = Wn[(size_t)o * H_DIM + i];
    size_t idx =
        ((size_t)((o >> 5) * NIT + (i >> 4)) * 64 + ((i >> 3) & 1) * 32 +
         (o & 31)) * 8 + (i & 7);
    Whi[idx] = f2bf(w * a);
    part += w * c;
  }
  __shared__ float red[256];
  red[tid] = part;
  __syncthreads();
  for (int s = 128; s > 0; s >>= 1) {
    if (tid < s) red[tid] += red[tid + s];
    __syncthreads();
  }
  if (tid == 0) bf[o] = bn[o] + red[0];
}

// ---------------------------------------------------------------------------
// Final: out[b,c] = sum_i (s5[T-1,b,i]*a5[i] + c5[i]) * Wout[c,i] + bout[c]
// s5 packed: t=2047 is the HIGH half of packed item i=1023.
// ---------------------------------------------------------------------------
__global__ __launch_bounds__(64) void final_out(const uint* __restrict__ s5,
                                                const float* __restrict__ stats,
                                                const float* __restrict__ gamma,
                                                const float* __restrict__ beta,
                                                const float* __restrict__ Wout,
                                                const float* __restrict__ bout,
                                                float* __restrict__ out) {
  const int b = blockIdx.x / C_DIM, cls = blockIdx.x % C_DIM;
  const int lane = threadIdx.x;
  constexpr float invTB = 1.f / (float)(T_DIM * B_DIM);
  const uint* srow =
      s5 + (size_t)(T_DIM / 2 - 1) * B_DIM * H_DIM + (size_t)b * H_DIM;
  float part = 0.f;
  for (int i = lane; i < H_DIM; i += 64) {
    float mean = stats[i] * invTB;
    float var = stats[H_DIM + i] * invTB - mean * mean;
    float a = gamma[i] * rsqrtf(var + BN_EPS);
    float c = beta[i] - mean * a;
    float sval = __uint_as_float(srow[i] & 0xffff0000u);
    part += (sval * a + c) * Wout[(size_t)cls * H_DIM + i];
  }
#pragma unroll
  for (int off = 32; off > 0; off >>= 1) part += __shfl_down(part, off);
  if (lane == 0) out[b * C_DIM + cls] = part + bout[cls];
}

// ---------------------------------------------------------------------------
extern "C" void kernel_launch(void* const* d_in, const int* in_sizes, int n_in,
                              void* d_out, int out_size, void* d_ws,
                              size_t ws_size, hipStream_t stream) {
  const float* x     = (const float*)d_in[0];
  const float* W0    = (const float*)d_in[1];
  const float* b0    = (const float*)d_in[2];
  const float* Wh    = (const float*)d_in[3];
  const float* bh    = (const float*)d_in[4];
  const float* u     = (const float*)d_in[5];
  const float* gamma = (const float*)d_in[6];
  const float* beta  = (const float*)d_in[7];
  const float* Wout  = (const float*)d_in[8];
  const float* bout  = (const float*)d_in[9];
  float* out = (float*)d_out;

  const size_t need = 2 * PKN * sizeof(uint) +
                      (size_t)H_DIM * H_DIM * sizeof(unsigned short) +
                      3 * H_DIM * sizeof(float);
  if (ws_size < need) {
    fill_sentinel<<<1, 64, 0, stream>>>(out, out_size);
    return;
  }

  uint* bufA = (uint*)d_ws;                             // 64 MB: z
  uint* bufB = bufA + PKN;                              // 64 MB: s
  unsigned short* Whi = (unsigned short*)(bufB + PKN);  // 512 KB
  float* bf = (float*)(Whi + (size_t)H_DIM * H_DIM);    // 2 KB
  float* stats = bf + H_DIM;                            // 4 KB

  const int gemm_blocks = TB / ROWS;  // 1024
  const int scan_blocks = (B_DIM * H_DIM) / 64;  // 256

  // ---- layer 0: x (f32, K=128, BKC=64 -> NC=2 pipelined) -> bufA (z) ----
  convert_w<D_DIM><<<(H_DIM * D_DIM + 255) / 256, 256, 0, stream>>>(W0, Whi);
  gemm_mfma<D_DIM, 64, false><<<gemm_blocks, 512, 0, stream>>>(x, Whi, b0,
                                                               bufA, stats);
  indrnn_scan<<<scan_blocks, 64, 0, stream>>>(bufA, bufB, u, stats);

  // ---- layers 1..5: ping-pong (s in B -> z in A -> s in B) ----
  for (int l = 1; l < L_DIM; ++l) {
    bn_fold<<<H_DIM, 256, 0, stream>>>(
        stats, gamma + (size_t)(l - 1) * H_DIM, beta + (size_t)(l - 1) * H_DIM,
        Wh + (size_t)(l - 1) * H_DIM * H_DIM, bh + (size_t)(l - 1) * H_DIM,
        Whi, bf);
    gemm_mfma<H_DIM, 128, true><<<gemm_blocks, 512, 0, stream>>>(
        bufB, Whi, bf, bufA, stats);
    indrnn_scan<<<scan_blocks, 64, 0, stream>>>(bufA, bufB,
                                                u + (size_t)l * H_DIM, stats);
  }

  // ---- final projection (BN of layer 5 applied on the fly) ----
  final_out<<<B_DIM * C_DIM, 64, 0, stream>>>(
      bufB, stats, gamma + 5 * (size_t)H_DIM, beta + 5 * (size_t)H_DIM, Wout,
      bout, out);
}

// Round 21
// 514.015 us; speedup vs baseline: 1.1876x; 1.1478x over previous
//
#include <hip/hip_runtime.h>

#define T_DIM 2048
#define B_DIM 32
#define D_DIM 128
#define H_DIM 512
#define L_DIM 6
#define C_DIM 10
#define BN_EPS 1e-5f

constexpr int TB = T_DIM * B_DIM;           // 65536 rows (t-major, then b)
constexpr size_t TBH = (size_t)TB * H_DIM;  // 33,554,432 elements
constexpr size_t PKN = TBH / 2;             // packed u32 count (64 MB)
constexpr int NCH_CHAINS = B_DIM * H_DIM;   // 16384 chains
constexpr int NSEG = 16;                    // segments per chain
constexpr int SEGI = (T_DIM / 2) / NSEG;    // 64 packed items per segment

typedef short s16x8 __attribute__((ext_vector_type(8)));
typedef float f32x16 __attribute__((ext_vector_type(16)));

// ---- bf16 helpers (bit-level, RNE) ----
__device__ inline unsigned short f2bf(float f) {
  unsigned u = __float_as_uint(f);
  unsigned r = (u + 0x7FFFu + ((u >> 16) & 1u)) >> 16;
  return (unsigned short)r;
}
__device__ inline float bf2f(unsigned short b) {
  return __uint_as_float((unsigned)b << 16);
}

// De-interleave 8 packed u32 (evenT | oddT<<16) into two planar s16x8 in LDS.
__device__ inline void destage(uint4 q0, uint4 q1, unsigned short* dlo,
                               unsigned short* dhi) {
  uint4 lo, hi;
  lo.x = __builtin_amdgcn_perm(q0.y, q0.x, 0x05040100u);
  lo.y = __builtin_amdgcn_perm(q0.w, q0.z, 0x05040100u);
  lo.z = __builtin_amdgcn_perm(q1.y, q1.x, 0x05040100u);
  lo.w = __builtin_amdgcn_perm(q1.w, q1.z, 0x05040100u);
  hi.x = __builtin_amdgcn_perm(q0.y, q0.x, 0x07060302u);
  hi.y = __builtin_amdgcn_perm(q0.w, q0.z, 0x07060302u);
  hi.z = __builtin_amdgcn_perm(q1.y, q1.x, 0x07060302u);
  hi.w = __builtin_amdgcn_perm(q1.w, q1.z, 0x07060302u);
  *(uint4*)dlo = lo;
  *(uint4*)dhi = hi;
}

// ---------------------------------------------------------------------------
// bf16 MFMA GEMM over t-pair-packed activations (out-of-place ping-pong):
//   z[t,b,o] = sum_k s[t,b,k] * W[o,k] + bias[o],  N = 512 fixed.
// R17-proven structure: 512 threads (8 waves), wave = 64 rows x 64 cols;
// planar-bf16 LDS staging (store-side destage), 1-term MFMA with single
// bf16 W in pre-swizzled fragment order + ring-4 register prefetch;
// coalesced epilogue via LDS funnel. Zeroes stats from block 0.
// ---------------------------------------------------------------------------
#define ROWS 64

template <int K, int BKC, bool PACKED_IN>
__global__ __launch_bounds__(512, 4) void gemm_mfma(
    const void* src, const unsigned short* __restrict__ Whi,
    const float* __restrict__ bias, uint* __restrict__ dstP, float* stats) {
  constexpr int NC = K / BKC;      // 2 (layer 0) or 4 (K=512)
  constexpr int NITC = BKC / 16;   // MFMA k-steps per chunk
  constexpr int NIT = K / 16;
  constexpr int GM = BKC / 8 - 1;  // granule swizzle mask
  __shared__ __align__(16) unsigned short AhS[2][ROWS * BKC];

  const int tid = threadIdx.x;
  if (blockIdx.x == 0) {  // fold zero_stats into the GEMM
    stats[tid] = 0.f;
    stats[tid + 512] = 0.f;
  }
  const int lane = tid & 63;
  const int wave = tid >> 6;  // 0..7 = col-group of 64
  const int r31 = lane & 31;
  const int kg = lane >> 5;

  const size_t pbase = (size_t)blockIdx.x * 16384;  // block's u32 region
  const uint* srcP = (const uint*)src;
  const float* srcF = (const float*)src;
  const size_t row0 = (size_t)blockIdx.x * ROWS;  // f32-path row base

  const unsigned short* pWh0 =
      Whi + ((size_t)(wave * 2 + 0) * NIT * 64 + lane) * 8;
  const unsigned short* pWh1 =
      Whi + ((size_t)(wave * 2 + 1) * NIT * 64 + lane) * 8;

  const int sr0 = tid >> 4, sk0 = tid & 15;
  const int ss0 = sr0 * BKC + ((sk0 ^ (sr0 & GM)) << 3);
  const int ss1 = (sr0 + 32) * BKC + ((sk0 ^ ((sr0 + 32) & GM)) << 3);
  const int srf = tid >> 3, skf = tid & 7;
  const int ssf = srf * BKC + ((skf ^ (srf & GM)) << 3);

  auto cvt8 = [&](float4 a, float4 b) {
    float vv[8] = {a.x, a.y, a.z, a.w, b.x, b.y, b.z, b.w};
    s16x8 hi;
#pragma unroll
    for (int j = 0; j < 8; ++j) hi[j] = (short)f2bf(vv[j]);
    return hi;
  };

  // ---- prologue: stage chunk 0 ----
  if (PACKED_IN) {
    uint4 q0 = *(const uint4*)(srcP + pbase + sr0 * 512 + sk0 * 8);
    uint4 q1 = *(const uint4*)(srcP + pbase + sr0 * 512 + sk0 * 8 + 4);
    destage(q0, q1, &AhS[0][ss0], &AhS[0][ss1]);
  } else {
    const size_t g = (row0 + srf) * K + skf * 8;
    *(s16x8*)&AhS[0][ssf] =
        cvt8(*(const float4*)(srcF + g), *(const float4*)(srcF + g + 4));
  }
  // ---- W ring prologue: fragments itg=0,1,2 into slots 0,1,2 ----
  s16x8 whr[4][2];
#pragma unroll
  for (int s = 0; s < 3; ++s) {
    whr[s][0] = *(const s16x8*)(pWh0 + (size_t)s * 512);
    whr[s][1] = *(const s16x8*)(pWh1 + (size_t)s * 512);
  }
  __syncthreads();

  f32x16 acc[2][2] = {};
  uint4 q0, q1;   // in-flight next-chunk A (packed)
  float4 f0, f1;  // in-flight next-chunk A (f32)
#pragma unroll
  for (int c = 0; c < NC; ++c) {
    if (c + 1 < NC) {  // issue next chunk's loads (hide under MFMAs)
      if (PACKED_IN) {
        q0 = *(const uint4*)(srcP + pbase + sr0 * 512 + (c + 1) * BKC +
                             sk0 * 8);
        q1 = *(const uint4*)(srcP + pbase + sr0 * 512 + (c + 1) * BKC +
                             sk0 * 8 + 4);
      } else {
        const size_t g = (row0 + srf) * K + (c + 1) * BKC + skf * 8;
        f0 = *(const float4*)(srcF + g);
        f1 = *(const float4*)(srcF + g + 4);
      }
    }
    const int bsel = c & 1;
#pragma unroll
    for (int it = 0; it < NITC; ++it) {
      const int itg = c * NITC + it;
      const int sl = itg & 3;
      if (itg + 3 < NIT) {  // ring-4 W prefetch (3-step lookahead)
        const int sp = (itg + 3) & 3;
        whr[sp][0] = *(const s16x8*)(pWh0 + (size_t)(itg + 3) * 512);
        whr[sp][1] = *(const s16x8*)(pWh1 + (size_t)(itg + 3) * 512);
      }
      const int gi = it * 2 + kg;
      s16x8 ah[2];
#pragma unroll
      for (int rf = 0; rf < 2; ++rf) {
        const int row = rf * 32 + r31;
        ah[rf] =
            *(const s16x8*)&AhS[bsel][row * BKC + ((gi ^ (row & GM)) << 3)];
      }
#pragma unroll
      for (int cf = 0; cf < 2; ++cf)
#pragma unroll
        for (int rf = 0; rf < 2; ++rf)
          acc[rf][cf] = __builtin_amdgcn_mfma_f32_32x32x16_bf16(
              ah[rf], whr[sl][cf], acc[rf][cf], 0, 0, 0);
    }
    if (c + 1 < NC) {  // stage next chunk into the other LDS buffer
      const int nb = (c + 1) & 1;
      if (PACKED_IN) {
        destage(q0, q1, &AhS[nb][ss0], &AhS[nb][ss1]);
      } else {
        *(s16x8*)&AhS[nb][ssf] = cvt8(f0, f1);
      }
      __syncthreads();
    }
  }

  // ---- epilogue (coalesced via LDS funnel) ----
  {
    uint* Cs = (uint*)&AhS[0][0];
    constexpr int CAP = ROWS * BKC;
    constexpr int RP = CAP / 512;
    constexpr int NP = 32 / RP;
    constexpr int NQ = CAP / 2048;
    const int o0 = wave * 64 + r31;
    const float bb0 = bias[o0];
    const float bb1 = bias[o0 + 32];
    __syncthreads();
#pragma unroll
    for (int p = 0; p < NP; ++p) {
#pragma unroll
      for (int j = 0; j < RP / 2; ++j) {
        const int r = p * (RP / 2) + j;
        const int mb = (r & 3) + 8 * (r >> 2) + 4 * kg;
        const int lr = mb - p * RP;
        const float e0 = acc[0][0][r] + bb0;
        const float d0 = acc[1][0][r] + bb0;
        const float e1 = acc[0][1][r] + bb1;
        const float d1 = acc[1][1][r] + bb1;
        Cs[lr * 512 + o0] = (uint)f2bf(e0) | ((uint)f2bf(d0) << 16);
        Cs[lr * 512 + o0 + 32] = (uint)f2bf(e1) | ((uint)f2bf(d1) << 16);
      }
      __syncthreads();
#pragma unroll
      for (int qd = 0; qd < NQ; ++qd) {
        uint4 v = *(const uint4*)&Cs[qd * 2048 + tid * 4];
        *(uint4*)&dstP[pbase + (size_t)p * CAP + qd * 2048 + tid * 4] = v;
      }
      if (p + 1 < NP) __syncthreads();
    }
  }
}

// ---------------------------------------------------------------------------
// R21 segmented scan. h_t = max(z_t + u h_{t-1}, 0) composes as
// F(h) = max(A + B h, G): (A,B,G)_2 o (A,B,G)_1 =
// (A2+B2*A1, B2*B1, max(A2+B2*G1, G2)). 16 segments x 128 t per chain.
//
// Phase A: per (chain c, segment j) compute A (linear part) and G (scan
// from 0) over packed z. 262144 threads = 16 waves/CU -- breaks the
// 256-wave cap that held the serial scan at 1.7 TB/s (R17-R20).
// ---------------------------------------------------------------------------
__global__ __launch_bounds__(256) void scan_seg_reduce(
    const uint* __restrict__ z, const float* __restrict__ u,
    float* __restrict__ segA, float* __restrict__ segG) {
  const int g = blockIdx.x * 256 + threadIdx.x;  // 0..262143
  const int c = g & (NCH_CHAINS - 1);
  const int j = g >> 14;
  const float uu = u[c & (H_DIM - 1)];
  const uint* p = z + c + (size_t)j * SEGI * NCH_CHAINS;
  float A = 0.f, G = -1.0e30f;
  constexpr int CH = 16;
  uint va[CH], vb[CH];

#define LOADA(dst, ck)                                          \
  _Pragma("unroll") for (int q = 0; q < CH; ++q) dst[q] =       \
      p[(size_t)((ck) * CH + q) * NCH_CHAINS];
#define COMPA(dst)                                              \
  _Pragma("unroll") for (int q = 0; q < CH; ++q) {              \
    uint pk = dst[q];                                           \
    float ze = __uint_as_float(pk << 16);                       \
    float zo = __uint_as_float(pk & 0xffff0000u);               \
    A = fmaf(uu, A, ze);                                        \
    G = fmaxf(fmaf(uu, G, ze), 0.f);                            \
    A = fmaf(uu, A, zo);                                        \
    G = fmaxf(fmaf(uu, G, zo), 0.f);                            \
  }

  LOADA(va, 0)
  LOADA(vb, 1)
  COMPA(va)
  LOADA(va, 2)
  COMPA(vb)
  LOADA(vb, 3)
  COMPA(va)
  COMPA(vb)
#undef LOADA
#undef COMPA
  segA[(size_t)j * NCH_CHAINS + c] = A;
  segG[(size_t)j * NCH_CHAINS + c] = G;
}

// ---------------------------------------------------------------------------
// Phase B: per chain, serial 16-step combine. B = u^128 (7 squarings).
// Overwrites segA[j] with the segment's INCOMING h (h before segment j).
// ---------------------------------------------------------------------------
__global__ __launch_bounds__(256) void scan_seg_combine(
    const float* __restrict__ u, float* __restrict__ segA,
    const float* __restrict__ segG) {
  const int c = blockIdx.x * 256 + threadIdx.x;  // 0..16383
  float B = u[c & (H_DIM - 1)];
#pragma unroll
  for (int q = 0; q < 7; ++q) B *= B;  // u^128
  float Aj[NSEG], Gj[NSEG];
#pragma unroll
  for (int j = 0; j < NSEG; ++j) {
    Aj[j] = segA[(size_t)j * NCH_CHAINS + c];
    Gj[j] = segG[(size_t)j * NCH_CHAINS + c];
  }
  float h = 0.f;
#pragma unroll
  for (int j = 0; j < NSEG; ++j) {
    segA[(size_t)j * NCH_CHAINS + c] = h;  // incoming h for segment j
    h = fmaxf(fmaf(B, h, Aj[j]), Gj[j]);
  }
}

// ---------------------------------------------------------------------------
// Phase C: replay each segment from its boundary h; write packed bf16 s
// (bit-RNE) out-of-place; accumulate stats on the ROUNDED s.
// ---------------------------------------------------------------------------
__global__ __launch_bounds__(256) void scan_seg_apply(
    const uint* __restrict__ z, uint* __restrict__ sdst,
    const float* __restrict__ u, const float* __restrict__ hin,
    float* __restrict__ stats) {
  const int g = blockIdx.x * 256 + threadIdx.x;  // 0..262143
  const int c = g & (NCH_CHAINS - 1);
  const int j = g >> 14;
  const int hch = c & (H_DIM - 1);
  const float uu = u[hch];
  float hh = hin[(size_t)j * NCH_CHAINS + c];
  float sum = 0.f, sumsq = 0.f;
  const uint* ps = z + c + (size_t)j * SEGI * NCH_CHAINS;
  uint* pd = sdst + c + (size_t)j * SEGI * NCH_CHAINS;
  constexpr int CH = 16;
  uint va[CH], vb[CH];

#define LOADC(dst, ck)                                          \
  _Pragma("unroll") for (int q = 0; q < CH; ++q) dst[q] =       \
      ps[(size_t)((ck) * CH + q) * NCH_CHAINS];
#define COMPC(dst)                                              \
  _Pragma("unroll") for (int q = 0; q < CH; ++q) {              \
    uint pk = dst[q];                                           \
    float ze = __uint_as_float(pk << 16);                       \
    float zo = __uint_as_float(pk & 0xffff0000u);               \
    hh = fmaxf(ze + uu * hh, 0.f);                              \
    unsigned short he = f2bf(hh);                               \
    float se = bf2f(he);                                        \
    sum += se; sumsq += se * se;                                \
    hh = fmaxf(zo + uu * hh, 0.f);                              \
    unsigned short ho = f2bf(hh);                               \
    float so = bf2f(ho);                                        \
    sum += so; sumsq += so * so;                                \
    dst[q] = (uint)he | ((uint)ho << 16);                       \
  }
#define STOREC(dst, ck)                                         \
  _Pragma("unroll") for (int q = 0; q < CH; ++q)                \
      pd[(size_t)((ck) * CH + q) * NCH_CHAINS] = dst[q];

  LOADC(va, 0)
  LOADC(vb, 1)
  COMPC(va)
  STOREC(va, 0)
  LOADC(va, 2)
  COMPC(vb)
  STOREC(vb, 1)
  LOADC(vb, 3)
  COMPC(va)
  STOREC(va, 2)
  COMPC(vb)
  STOREC(vb, 3)
#undef LOADC
#undef COMPC
#undef STOREC
  atomicAdd(&stats[hch], sum);
  atomicAdd(&stats[H_DIM + hch], sumsq);
}

__global__ __launch_bounds__(64) void fill_sentinel(float* __restrict__ out,
                                                    int n) {
  for (int i = threadIdx.x; i < n; i += 64) out[i] = 1.0e6f;
}

// ---------------------------------------------------------------------------
// Convert raw f32 weights (layer 0) to bf16 in fragment-swizzled order.
// ---------------------------------------------------------------------------
template <int K>
__global__ __launch_bounds__(256) void convert_w(
    const float* __restrict__ W, unsigned short* __restrict__ Whi) {
  constexpr int NIT = K / 16;
  int i = blockIdx.x * 256 + threadIdx.x;
  if (i < H_DIM * K) {
    int o = i / K, k = i % K;
    size_t idx =
        ((size_t)((o >> 5) * NIT + (k >> 4)) * 64 + ((k >> 3) & 1) * 32 +
         (o & 31)) * 8 + (k & 7);
    Whi[idx] = f2bf(W[i]);
  }
}

// ---------------------------------------------------------------------------
// Fold BN of previous layer into next layer's weights, emit swizzled bf16.
// ---------------------------------------------------------------------------
__global__ __launch_bounds__(256) void bn_fold(
    const float* __restrict__ stats, const float* __restrict__ gamma,
    const float* __restrict__ beta, const float* __restrict__ Wn,
    const float* __restrict__ bn, unsigned short* __restrict__ Whi,
    float* __restrict__ bf) {
  constexpr int NIT = H_DIM / 16;
  const int o = blockIdx.x;
  const int tid = threadIdx.x;
  constexpr float invTB = 1.f / (float)(T_DIM * B_DIM);
  float part = 0.f;
  for (int i = tid; i < H_DIM; i += 256) {
    float mean = stats[i] * invTB;
    float var = stats[H_DIM + i] * invTB - mean * mean;
    float a = gamma[i] * rsqrtf(var + BN_EPS);
    float c = beta[i] - mean * a;
    float w = Wn[(size_t)o * H_DIM + i];
    size_t idx =
        ((size_t)((o >> 5) * NIT + (i >> 4)) * 64 + ((i >> 3) & 1) * 32 +
         (o & 31)) * 8 + (i & 7);
    Whi[idx] = f2bf(w * a);
    part += w * c;
  }
  __shared__ float red[256];
  red[tid] = part;
  __syncthreads();
  for (int s = 128; s > 0; s >>= 1) {
    if (tid < s) red[tid] += red[tid + s];
    __syncthreads();
  }
  if (tid == 0) bf[o] = bn[o] + red[0];
}

// ---------------------------------------------------------------------------
// Final: out[b,c] = sum_i (s5[T-1,b,i]*a5[i] + c5[i]) * Wout[c,i] + bout[c]
// ---------------------------------------------------------------------------
__global__ __launch_bounds__(64) void final_out(const uint* __restrict__ s5,
                                                const float* __restrict__ stats,
                                                const float* __restrict__ gamma,
                                                const float* __restrict__ beta,
                                                const float* __restrict__ Wout,
                                                const float* __restrict__ bout,
                                                float* __restrict__ out) {
  const int b = blockIdx.x / C_DIM, cls = blockIdx.x % C_DIM;
  const int lane = threadIdx.x;
  constexpr float invTB = 1.f / (float)(T_DIM * B_DIM);
  const uint* srow =
      s5 + (size_t)(T_DIM / 2 - 1) * B_DIM * H_DIM + (size_t)b * H_DIM;
  float part = 0.f;
  for (int i = lane; i < H_DIM; i += 64) {
    float mean = stats[i] * invTB;
    float var = stats[H_DIM + i] * invTB - mean * mean;
    float a = gamma[i] * rsqrtf(var + BN_EPS);
    float c = beta[i] - mean * a;
    float sval = __uint_as_float(srow[i] & 0xffff0000u);
    part += (sval * a + c) * Wout[(size_t)cls * H_DIM + i];
  }
#pragma unroll
  for (int off = 32; off > 0; off >>= 1) part += __shfl_down(part, off);
  if (lane == 0) out[b * C_DIM + cls] = part + bout[cls];
}

// ---------------------------------------------------------------------------
extern "C" void kernel_launch(void* const* d_in, const int* in_sizes, int n_in,
                              void* d_out, int out_size, void* d_ws,
                              size_t ws_size, hipStream_t stream) {
  const float* x     = (const float*)d_in[0];
  const float* W0    = (const float*)d_in[1];
  const float* b0    = (const float*)d_in[2];
  const float* Wh    = (const float*)d_in[3];
  const float* bh    = (const float*)d_in[4];
  const float* u     = (const float*)d_in[5];
  const float* gamma = (const float*)d_in[6];
  const float* beta  = (const float*)d_in[7];
  const float* Wout  = (const float*)d_in[8];
  const float* bout  = (const float*)d_in[9];
  float* out = (float*)d_out;

  const size_t segN = (size_t)NSEG * NCH_CHAINS;  // 262144 f32 per buffer
  const size_t need = 2 * PKN * sizeof(uint) +
                      (size_t)H_DIM * H_DIM * sizeof(unsigned short) +
                      2 * segN * sizeof(float) + 3 * H_DIM * sizeof(float);
  if (ws_size < need) {
    fill_sentinel<<<1, 64, 0, stream>>>(out, out_size);
    return;
  }

  uint* bufA = (uint*)d_ws;                             // 64 MB: z
  uint* bufB = bufA + PKN;                              // 64 MB: s
  unsigned short* Whi = (unsigned short*)(bufB + PKN);  // 512 KB
  float* segA = (float*)(Whi + (size_t)H_DIM * H_DIM);  // 1 MB
  float* segG = segA + segN;                            // 1 MB
  float* bf = segG + segN;                              // 2 KB
  float* stats = bf + H_DIM;                            // 4 KB

  const int gemm_blocks = TB / ROWS;        // 1024
  const int segAB = NSEG * NCH_CHAINS / 256;  // 1024 blocks for A/C

  // ---- layer 0: x (f32, K=128, BKC=64 -> NC=2 pipelined) -> bufA (z) ----
  convert_w<D_DIM><<<(H_DIM * D_DIM + 255) / 256, 256, 0, stream>>>(W0, Whi);
  gemm_mfma<D_DIM, 64, false><<<gemm_blocks, 512, 0, stream>>>(x, Whi, b0,
                                                               bufA, stats);
  scan_seg_reduce<<<segAB, 256, 0, stream>>>(bufA, u, segA, segG);
  scan_seg_combine<<<NCH_CHAINS / 256, 256, 0, stream>>>(u, segA, segG);
  scan_seg_apply<<<segAB, 256, 0, stream>>>(bufA, bufB, u, segA, stats);

  // ---- layers 1..5: ping-pong (s in B -> z in A -> s in B) ----
  for (int l = 1; l < L_DIM; ++l) {
    const float* ul = u + (size_t)l * H_DIM;
    bn_fold<<<H_DIM, 256, 0, stream>>>(
        stats, gamma + (size_t)(l - 1) * H_DIM, beta + (size_t)(l - 1) * H_DIM,
        Wh + (size_t)(l - 1) * H_DIM * H_DIM, bh + (size_t)(l - 1) * H_DIM,
        Whi, bf);
    gemm_mfma<H_DIM, 128, true><<<gemm_blocks, 512, 0, stream>>>(
        bufB, Whi, bf, bufA, stats);
    scan_seg_reduce<<<segAB, 256, 0, stream>>>(bufA, ul, segA, segG);
    scan_seg_combine<<<NCH_CHAINS / 256, 256, 0, stream>>>(ul, segA, segG);
    scan_seg_apply<<<segAB, 256, 0, stream>>>(bufA, bufB, ul, segA, stats);
  }

  // ---- final projection (BN of layer 5 applied on the fly) ----
  final_out<<<B_DIM * C_DIM, 64, 0, stream>>>(
      bufB, stats, gamma + 5 * (size_t)H_DIM, beta + 5 * (size_t)H_DIM, Wout,
      bout, out);
}

// Round 22
// 478.188 us; speedup vs baseline: 1.2766x; 1.0749x over previous
//
#include <hip/hip_runtime.h>

#define T_DIM 2048
#define B_DIM 32
#define D_DIM 128
#define H_DIM 512
#define L_DIM 6
#define C_DIM 10
#define BN_EPS 1e-5f

constexpr int TB = T_DIM * B_DIM;           // 65536 rows (t-major, then b)
constexpr size_t TBH = (size_t)TB * H_DIM;  // 33,554,432 elements
constexpr size_t PKN = TBH / 2;             // packed u32 count (64 MB)
constexpr int NCH_CHAINS = B_DIM * H_DIM;   // 16384 chains
constexpr int NSEG = 16;                    // segments per chain
constexpr int SEGI = (T_DIM / 2) / NSEG;    // 64 packed items per segment

typedef short s16x8 __attribute__((ext_vector_type(8)));
typedef float f32x16 __attribute__((ext_vector_type(16)));

// ---- bf16 helpers (bit-level, RNE) ----
__device__ inline unsigned short f2bf(float f) {
  unsigned u = __float_as_uint(f);
  unsigned r = (u + 0x7FFFu + ((u >> 16) & 1u)) >> 16;
  return (unsigned short)r;
}
__device__ inline float bf2f(unsigned short b) {
  return __uint_as_float((unsigned)b << 16);
}

// De-interleave 8 packed u32 (evenT | oddT<<16) into two planar s16x8 in LDS.
__device__ inline void destage(uint4 q0, uint4 q1, unsigned short* dlo,
                               unsigned short* dhi) {
  uint4 lo, hi;
  lo.x = __builtin_amdgcn_perm(q0.y, q0.x, 0x05040100u);
  lo.y = __builtin_amdgcn_perm(q0.w, q0.z, 0x05040100u);
  lo.z = __builtin_amdgcn_perm(q1.y, q1.x, 0x05040100u);
  lo.w = __builtin_amdgcn_perm(q1.w, q1.z, 0x05040100u);
  hi.x = __builtin_amdgcn_perm(q0.y, q0.x, 0x07060302u);
  hi.y = __builtin_amdgcn_perm(q0.w, q0.z, 0x07060302u);
  hi.z = __builtin_amdgcn_perm(q1.y, q1.x, 0x07060302u);
  hi.w = __builtin_amdgcn_perm(q1.w, q1.z, 0x07060302u);
  *(uint4*)dlo = lo;
  *(uint4*)dhi = hi;
}

// ---------------------------------------------------------------------------
// bf16 MFMA GEMM over t-pair-packed activations (out-of-place ping-pong):
//   z[t,b,o] = sum_k s[t,b,k] * W[o,k] + bias[o],  N = 512 fixed.
// R17-proven structure: 512 threads (8 waves), wave = 64 rows x 64 cols;
// planar-bf16 LDS staging (store-side destage), 1-term MFMA with single
// bf16 W in pre-swizzled fragment order + ring-4 register prefetch;
// coalesced epilogue via LDS funnel. Zeroes stats from block 0.
// ---------------------------------------------------------------------------
#define ROWS 64

template <int K, int BKC, bool PACKED_IN>
__global__ __launch_bounds__(512, 4) void gemm_mfma(
    const void* src, const unsigned short* __restrict__ Whi,
    const float* __restrict__ bias, uint* __restrict__ dstP, float* stats) {
  constexpr int NC = K / BKC;      // 2 (layer 0) or 4 (K=512)
  constexpr int NITC = BKC / 16;   // MFMA k-steps per chunk
  constexpr int NIT = K / 16;
  constexpr int GM = BKC / 8 - 1;  // granule swizzle mask
  __shared__ __align__(16) unsigned short AhS[2][ROWS * BKC];

  const int tid = threadIdx.x;
  if (blockIdx.x == 0) {  // fold zero_stats into the GEMM
    stats[tid] = 0.f;
    stats[tid + 512] = 0.f;
  }
  const int lane = tid & 63;
  const int wave = tid >> 6;  // 0..7 = col-group of 64
  const int r31 = lane & 31;
  const int kg = lane >> 5;

  const size_t pbase = (size_t)blockIdx.x * 16384;  // block's u32 region
  const uint* srcP = (const uint*)src;
  const float* srcF = (const float*)src;
  const size_t row0 = (size_t)blockIdx.x * ROWS;  // f32-path row base

  const unsigned short* pWh0 =
      Whi + ((size_t)(wave * 2 + 0) * NIT * 64 + lane) * 8;
  const unsigned short* pWh1 =
      Whi + ((size_t)(wave * 2 + 1) * NIT * 64 + lane) * 8;

  const int sr0 = tid >> 4, sk0 = tid & 15;
  const int ss0 = sr0 * BKC + ((sk0 ^ (sr0 & GM)) << 3);
  const int ss1 = (sr0 + 32) * BKC + ((sk0 ^ ((sr0 + 32) & GM)) << 3);
  const int srf = tid >> 3, skf = tid & 7;
  const int ssf = srf * BKC + ((skf ^ (srf & GM)) << 3);

  auto cvt8 = [&](float4 a, float4 b) {
    float vv[8] = {a.x, a.y, a.z, a.w, b.x, b.y, b.z, b.w};
    s16x8 hi;
#pragma unroll
    for (int j = 0; j < 8; ++j) hi[j] = (short)f2bf(vv[j]);
    return hi;
  };

  // ---- prologue: stage chunk 0 ----
  if (PACKED_IN) {
    uint4 q0 = *(const uint4*)(srcP + pbase + sr0 * 512 + sk0 * 8);
    uint4 q1 = *(const uint4*)(srcP + pbase + sr0 * 512 + sk0 * 8 + 4);
    destage(q0, q1, &AhS[0][ss0], &AhS[0][ss1]);
  } else {
    const size_t g = (row0 + srf) * K + skf * 8;
    *(s16x8*)&AhS[0][ssf] =
        cvt8(*(const float4*)(srcF + g), *(const float4*)(srcF + g + 4));
  }
  // ---- W ring prologue: fragments itg=0,1,2 into slots 0,1,2 ----
  s16x8 whr[4][2];
#pragma unroll
  for (int s = 0; s < 3; ++s) {
    whr[s][0] = *(const s16x8*)(pWh0 + (size_t)s * 512);
    whr[s][1] = *(const s16x8*)(pWh1 + (size_t)s * 512);
  }
  __syncthreads();

  f32x16 acc[2][2] = {};
  uint4 q0, q1;   // in-flight next-chunk A (packed)
  float4 f0, f1;  // in-flight next-chunk A (f32)
#pragma unroll
  for (int c = 0; c < NC; ++c) {
    if (c + 1 < NC) {  // issue next chunk's loads (hide under MFMAs)
      if (PACKED_IN) {
        q0 = *(const uint4*)(srcP + pbase + sr0 * 512 + (c + 1) * BKC +
                             sk0 * 8);
        q1 = *(const uint4*)(srcP + pbase + sr0 * 512 + (c + 1) * BKC +
                             sk0 * 8 + 4);
      } else {
        const size_t g = (row0 + srf) * K + (c + 1) * BKC + skf * 8;
        f0 = *(const float4*)(srcF + g);
        f1 = *(const float4*)(srcF + g + 4);
      }
    }
    const int bsel = c & 1;
#pragma unroll
    for (int it = 0; it < NITC; ++it) {
      const int itg = c * NITC + it;
      const int sl = itg & 3;
      if (itg + 3 < NIT) {  // ring-4 W prefetch (3-step lookahead)
        const int sp = (itg + 3) & 3;
        whr[sp][0] = *(const s16x8*)(pWh0 + (size_t)(itg + 3) * 512);
        whr[sp][1] = *(const s16x8*)(pWh1 + (size_t)(itg + 3) * 512);
      }
      const int gi = it * 2 + kg;
      s16x8 ah[2];
#pragma unroll
      for (int rf = 0; rf < 2; ++rf) {
        const int row = rf * 32 + r31;
        ah[rf] =
            *(const s16x8*)&AhS[bsel][row * BKC + ((gi ^ (row & GM)) << 3)];
      }
#pragma unroll
      for (int cf = 0; cf < 2; ++cf)
#pragma unroll
        for (int rf = 0; rf < 2; ++rf)
          acc[rf][cf] = __builtin_amdgcn_mfma_f32_32x32x16_bf16(
              ah[rf], whr[sl][cf], acc[rf][cf], 0, 0, 0);
    }
    if (c + 1 < NC) {  // stage next chunk into the other LDS buffer
      const int nb = (c + 1) & 1;
      if (PACKED_IN) {
        destage(q0, q1, &AhS[nb][ss0], &AhS[nb][ss1]);
      } else {
        *(s16x8*)&AhS[nb][ssf] = cvt8(f0, f1);
      }
      __syncthreads();
    }
  }

  // ---- epilogue (coalesced via LDS funnel) ----
  {
    uint* Cs = (uint*)&AhS[0][0];
    constexpr int CAP = ROWS * BKC;
    constexpr int RP = CAP / 512;
    constexpr int NP = 32 / RP;
    constexpr int NQ = CAP / 2048;
    const int o0 = wave * 64 + r31;
    const float bb0 = bias[o0];
    const float bb1 = bias[o0 + 32];
    __syncthreads();
#pragma unroll
    for (int p = 0; p < NP; ++p) {
#pragma unroll
      for (int j = 0; j < RP / 2; ++j) {
        const int r = p * (RP / 2) + j;
        const int mb = (r & 3) + 8 * (r >> 2) + 4 * kg;
        const int lr = mb - p * RP;
        const float e0 = acc[0][0][r] + bb0;
        const float d0 = acc[1][0][r] + bb0;
        const float e1 = acc[0][1][r] + bb1;
        const float d1 = acc[1][1][r] + bb1;
        Cs[lr * 512 + o0] = (uint)f2bf(e0) | ((uint)f2bf(d0) << 16);
        Cs[lr * 512 + o0 + 32] = (uint)f2bf(e1) | ((uint)f2bf(d1) << 16);
      }
      __syncthreads();
#pragma unroll
      for (int qd = 0; qd < NQ; ++qd) {
        uint4 v = *(const uint4*)&Cs[qd * 2048 + tid * 4];
        *(uint4*)&dstP[pbase + (size_t)p * CAP + qd * 2048 + tid * 4] = v;
      }
      if (p + 1 < NP) __syncthreads();
    }
  }
}

// ---------------------------------------------------------------------------
// R22 FUSED segmented scan: one kernel per layer, z read ONCE into registers.
// h_t = max(z_t + u h_{t-1}, 0) composes as F(h)=max(A+B h, G):
//   append step: A <- z + u*A; G <- max(z + u*G, 0); B is implicit (u^len).
// Block = 64 consecutive chains x all 16 segments (1024 threads, 16 waves;
// wave = one segment x 64 chains -> coalesced 256B/instr). Per thread:
// load its segment's 64 packed u32 into REGISTERS (64-deep load pipeline),
// fold (A,G), LDS-exchange (8 KB, conflict-free), serial exclusive combine
// with B=u^128 (identical order to R21's phase B -> bit-identical h), then
// replay from registers, write packed bf16 s + stats.
// Eliminates R21's 64MB/layer z re-read, segA/segG buffers, 2 launches/layer.
// ---------------------------------------------------------------------------
__global__ __launch_bounds__(1024, 4) void indrnn_scan_seg(
    const uint* __restrict__ z, uint* __restrict__ sdst,
    const float* __restrict__ u, float* __restrict__ stats) {
  __shared__ float Als[NSEG * 64];
  __shared__ float Gls[NSEG * 64];
  const int tid = threadIdx.x;
  const int j = tid >> 6;   // segment 0..15 (wave-uniform)
  const int cl = tid & 63;  // chain-in-block
  const int c = blockIdx.x * 64 + cl;
  const int hch = c & (H_DIM - 1);
  const float uu = u[hch];
  const uint* ps = z + c + (size_t)j * SEGI * NCH_CHAINS;
  uint* pd = sdst + c + (size_t)j * SEGI * NCH_CHAINS;

  // ---- load whole segment into registers ----
  uint v[SEGI];
#pragma unroll
  for (int q = 0; q < SEGI; ++q) v[q] = ps[(size_t)q * NCH_CHAINS];

  // ---- phase A: fold segment map (A = linear part, G = floor) ----
  float A = 0.f, G = -1.0e30f;
#pragma unroll
  for (int q = 0; q < SEGI; ++q) {
    const uint pk = v[q];
    const float ze = __uint_as_float(pk << 16);
    const float zo = __uint_as_float(pk & 0xffff0000u);
    A = fmaf(uu, A, ze);
    G = fmaxf(fmaf(uu, G, ze), 0.f);
    A = fmaf(uu, A, zo);
    G = fmaxf(fmaf(uu, G, zo), 0.f);
  }
  Als[tid] = A;  // row j, col cl
  Gls[tid] = G;
  __syncthreads();

  // ---- exclusive combine: incoming h for segment j ----
  float B = uu;
#pragma unroll
  for (int q = 0; q < 7; ++q) B *= B;  // u^128
  float hh = 0.f;
  for (int jp = 0; jp < j; ++jp)  // wave-uniform trip count
    hh = fmaxf(fmaf(B, hh, Als[jp * 64 + cl]), Gls[jp * 64 + cl]);

  // ---- phase C: replay from registers, write packed bf16 s + stats ----
  float sum = 0.f, sumsq = 0.f;
#pragma unroll
  for (int q = 0; q < SEGI; ++q) {
    const uint pk = v[q];
    const float ze = __uint_as_float(pk << 16);
    const float zo = __uint_as_float(pk & 0xffff0000u);
    hh = fmaxf(ze + uu * hh, 0.f);
    const unsigned short he = f2bf(hh);
    const float se = bf2f(he);
    sum += se;
    sumsq += se * se;
    hh = fmaxf(zo + uu * hh, 0.f);
    const unsigned short ho = f2bf(hh);
    const float so = bf2f(ho);
    sum += so;
    sumsq += so * so;
    pd[(size_t)q * NCH_CHAINS] = (uint)he | ((uint)ho << 16);
  }
  atomicAdd(&stats[hch], sum);
  atomicAdd(&stats[H_DIM + hch], sumsq);
}

__global__ __launch_bounds__(64) void fill_sentinel(float* __restrict__ out,
                                                    int n) {
  for (int i = threadIdx.x; i < n; i += 64) out[i] = 1.0e6f;
}

// ---------------------------------------------------------------------------
// Convert raw f32 weights (layer 0) to bf16 in fragment-swizzled order.
// ---------------------------------------------------------------------------
template <int K>
__global__ __launch_bounds__(256) void convert_w(
    const float* __restrict__ W, unsigned short* __restrict__ Whi) {
  constexpr int NIT = K / 16;
  int i = blockIdx.x * 256 + threadIdx.x;
  if (i < H_DIM * K) {
    int o = i / K, k = i % K;
    size_t idx =
        ((size_t)((o >> 5) * NIT + (k >> 4)) * 64 + ((k >> 3) & 1) * 32 +
         (o & 31)) * 8 + (k & 7);
    Whi[idx] = f2bf(W[i]);
  }
}

// ---------------------------------------------------------------------------
// Fold BN of previous layer into next layer's weights, emit swizzled bf16.
// ---------------------------------------------------------------------------
__global__ __launch_bounds__(256) void bn_fold(
    const float* __restrict__ stats, const float* __restrict__ gamma,
    const float* __restrict__ beta, const float* __restrict__ Wn,
    const float* __restrict__ bn, unsigned short* __restrict__ Whi,
    float* __restrict__ bf) {
  constexpr int NIT = H_DIM / 16;
  const int o = blockIdx.x;
  const int tid = threadIdx.x;
  constexpr float invTB = 1.f / (float)(T_DIM * B_DIM);
  float part = 0.f;
  for (int i = tid; i < H_DIM; i += 256) {
    float mean = stats[i] * invTB;
    float var = stats[H_DIM + i] * invTB - mean * mean;
    float a = gamma[i] * rsqrtf(var + BN_EPS);
    float c = beta[i] - mean * a;
    float w = Wn[(size_t)o * H_DIM + i];
    size_t idx =
        ((size_t)((o >> 5) * NIT + (i >> 4)) * 64 + ((i >> 3) & 1) * 32 +
         (o & 31)) * 8 + (i & 7);
    Whi[idx] = f2bf(w * a);
    part += w * c;
  }
  __shared__ float red[256];
  red[tid] = part;
  __syncthreads();
  for (int s = 128; s > 0; s >>= 1) {
    if (tid < s) red[tid] += red[tid + s];
    __syncthreads();
  }
  if (tid == 0) bf[o] = bn[o] + red[0];
}

// ---------------------------------------------------------------------------
// Final: out[b,c] = sum_i (s5[T-1,b,i]*a5[i] + c5[i]) * Wout[c,i] + bout[c]
// ---------------------------------------------------------------------------
__global__ __launch_bounds__(64) void final_out(const uint* __restrict__ s5,
                                                const float* __restrict__ stats,
                                                const float* __restrict__ gamma,
                                                const float* __restrict__ beta,
                                                const float* __restrict__ Wout,
                                                const float* __restrict__ bout,
                                                float* __restrict__ out) {
  const int b = blockIdx.x / C_DIM, cls = blockIdx.x % C_DIM;
  const int lane = threadIdx.x;
  constexpr float invTB = 1.f / (float)(T_DIM * B_DIM);
  const uint* srow =
      s5 + (size_t)(T_DIM / 2 - 1) * B_DIM * H_DIM + (size_t)b * H_DIM;
  float part = 0.f;
  for (int i = lane; i < H_DIM; i += 64) {
    float mean = stats[i] * invTB;
    float var = stats[H_DIM + i] * invTB - mean * mean;
    float a = gamma[i] * rsqrtf(var + BN_EPS);
    float c = beta[i] - mean * a;
    float sval = __uint_as_float(srow[i] & 0xffff0000u);
    part += (sval * a + c) * Wout[(size_t)cls * H_DIM + i];
  }
#pragma unroll
  for (int off = 32; off > 0; off >>= 1) part += __shfl_down(part, off);
  if (lane == 0) out[b * C_DIM + cls] = part + bout[cls];
}

// ---------------------------------------------------------------------------
extern "C" void kernel_launch(void* const* d_in, const int* in_sizes, int n_in,
                              void* d_out, int out_size, void* d_ws,
                              size_t ws_size, hipStream_t stream) {
  const float* x     = (const float*)d_in[0];
  const float* W0    = (const float*)d_in[1];
  const float* b0    = (const float*)d_in[2];
  const float* Wh    = (const float*)d_in[3];
  const float* bh    = (const float*)d_in[4];
  const float* u     = (const float*)d_in[5];
  const float* gamma = (const float*)d_in[6];
  const float* beta  = (const float*)d_in[7];
  const float* Wout  = (const float*)d_in[8];
  const float* bout  = (const float*)d_in[9];
  float* out = (float*)d_out;

  const size_t need = 2 * PKN * sizeof(uint) +
                      (size_t)H_DIM * H_DIM * sizeof(unsigned short) +
                      3 * H_DIM * sizeof(float);
  if (ws_size < need) {
    fill_sentinel<<<1, 64, 0, stream>>>(out, out_size);
    return;
  }

  uint* bufA = (uint*)d_ws;                             // 64 MB: z
  uint* bufB = bufA + PKN;                              // 64 MB: s
  unsigned short* Whi = (unsigned short*)(bufB + PKN);  // 512 KB
  float* bf = (float*)(Whi + (size_t)H_DIM * H_DIM);    // 2 KB
  float* stats = bf + H_DIM;                            // 4 KB

  const int gemm_blocks = TB / ROWS;         // 1024
  const int scan_blocks = NCH_CHAINS / 64;   // 256 blocks x 1024 threads

  // ---- layer 0: x (f32, K=128, BKC=64 -> NC=2 pipelined) -> bufA (z) ----
  convert_w<D_DIM><<<(H_DIM * D_DIM + 255) / 256, 256, 0, stream>>>(W0, Whi);
  gemm_mfma<D_DIM, 64, false><<<gemm_blocks, 512, 0, stream>>>(x, Whi, b0,
                                                               bufA, stats);
  indrnn_scan_seg<<<scan_blocks, 1024, 0, stream>>>(bufA, bufB, u, stats);

  // ---- layers 1..5: ping-pong (s in B -> z in A -> s in B) ----
  for (int l = 1; l < L_DIM; ++l) {
    const float* ul = u + (size_t)l * H_DIM;
    bn_fold<<<H_DIM, 256, 0, stream>>>(
        stats, gamma + (size_t)(l - 1) * H_DIM, beta + (size_t)(l - 1) * H_DIM,
        Wh + (size_t)(l - 1) * H_DIM * H_DIM, bh + (size_t)(l - 1) * H_DIM,
        Whi, bf);
    gemm_mfma<H_DIM, 128, true><<<gemm_blocks, 512, 0, stream>>>(
        bufB, Whi, bf, bufA, stats);
    indrnn_scan_seg<<<scan_blocks, 1024, 0, stream>>>(bufA, bufB, ul, stats);
  }

  // ---- final projection (BN of layer 5 applied on the fly) ----
  final_out<<<B_DIM * C_DIM, 64, 0, stream>>>(
      bufB, stats, gamma + 5 * (size_t)H_DIM, beta + 5 * (size_t)H_DIM, Wout,
      bout, out);
}